// Round 1
// baseline (342.589 us; speedup 1.0000x reference)
//
#include <hip/hip_runtime.h>
#include <hip/hip_bf16.h>
#include <cstdint>

typedef unsigned short u16;
typedef __bf16 bf16x8 __attribute__((ext_vector_type(8)));
typedef float f32x4 __attribute__((ext_vector_type(4)));

#define S_LEN 2048
#define NH 16
#define DK 64
#define DM 1024
#define M_TOT 4096   // B*S

__device__ __forceinline__ u16 f2bf(float f) {
  union { float f; uint32_t u; } c; c.f = f;
  uint32_t u = c.u;
  u += 0x7fffu + ((u >> 16) & 1u);   // RNE
  return (u16)(u >> 16);
}

__device__ __forceinline__ void gl_lds16(const void* gsrc, void* ldst) {
  __builtin_amdgcn_global_load_lds(
      (const __attribute__((address_space(1))) unsigned int*)gsrc,
      (__attribute__((address_space(3))) unsigned int*)ldst,
      16, 0, 0);
}

// ---------------- fp32 -> bf16 conversion (x + 4 weights) ----------------
__global__ __launch_bounds__(256) void convert_all(
    const float* x, const float* wq, const float* wk, const float* wv, const float* wo,
    u16* xb, u16* wqb, u16* wkb, u16* wvb, u16* wob)
{
  size_t i = ((size_t)blockIdx.x * 256 + threadIdx.x) * 4;
  const float* src; u16* dst; size_t off;
  if (i < 4194304u)      { src = x;  dst = xb;  off = i; }
  else if (i < 5242880u) { src = wq; dst = wqb; off = i - 4194304u; }
  else if (i < 6291456u) { src = wk; dst = wkb; off = i - 5242880u; }
  else if (i < 7340032u) { src = wv; dst = wvb; off = i - 6291456u; }
  else                   { src = wo; dst = wob; off = i - 7340032u; }
  float4 v = *(const float4*)(src + off);
  ushort4 o;
  o.x = f2bf(v.x); o.y = f2bf(v.y); o.z = f2bf(v.z); o.w = f2bf(v.w);
  *(ushort4*)(dst + off) = o;
}

// ---------------- RoPE cos/sin table: tab[pos*32 + i] = {cos, sin} ----------------
__global__ __launch_bounds__(256) void rope_tab_k(float2* tab) {
  int i = blockIdx.x * 256 + threadIdx.x;   // 65536 entries
  int pos = i >> 5, f = i & 31;
  float inv = powf(10000.0f, -(float)f / 32.0f);   // THETA^(-2f/64)
  float ang = (float)pos * inv;
  tab[i] = make_float2(cosf(ang), sinf(ang));
}

// ---------------- shared GEMM core: C(128x128) = A(MxK) * W(NxK)^T, bf16 MFMA ----------------
// LDS tiles XOR-swizzled: element (row, k) lives at byte row*128 + ((k*2) ^ ((row&7)<<4)).
// global_load_lds writes linearly (wave base + lane*16); source address pre-swizzled (rule #21).
__device__ __forceinline__ void gemm_core_128(
    const u16* A, const u16* W, int K, int m0, int n0,
    u16* ldsA, u16* ldsB, f32x4 (&acc)[4][4])
{
  const int tid = threadIdx.x;
  const int w = tid >> 6, lane = tid & 63;
  const int l15 = lane & 15, g = lane >> 4;
  const int wm = (w >> 1) * 64, wn = (w & 1) * 64;
  const int lrow = lane >> 3;                              // 0..7 within 8-row chunk
  const int scolb = ((lane & 7) * 16) ^ (lrow << 4);       // pre-swizzled source byte

  for (int kt = 0; kt < K; kt += 64) {
#pragma unroll
    for (int c = 0; c < 4; ++c) {
      const int rb = w * 32 + c * 8;                       // chunk row base (8 rows/chunk)
      const int row = rb + lrow;
      gl_lds16((const char*)(A + (size_t)(m0 + row) * K + kt) + scolb,
               (char*)ldsA + rb * 128);
      gl_lds16((const char*)(W + (size_t)(n0 + row) * K + kt) + scolb,
               (char*)ldsB + rb * 128);
    }
    __syncthreads();
#pragma unroll
    for (int ks = 0; ks < 2; ++ks) {
      bf16x8 af[4], bfr[4];
#pragma unroll
      for (int i = 0; i < 4; ++i) {
        const int ar = wm + i * 16 + l15;
        af[i] = *(const bf16x8*)((const char*)ldsA + ar * 128 +
                                 ((ks * 64 + g * 16) ^ ((ar & 7) << 4)));
        const int br = wn + i * 16 + l15;
        bfr[i] = *(const bf16x8*)((const char*)ldsB + br * 128 +
                                  ((ks * 64 + g * 16) ^ ((br & 7) << 4)));
      }
#pragma unroll
      for (int i = 0; i < 4; ++i)
#pragma unroll
        for (int j = 0; j < 4; ++j)
          acc[i][j] = __builtin_amdgcn_mfma_f32_16x16x32_bf16(af[i], bfr[j], acc[i][j], 0, 0, 0);
    }
    __syncthreads();
  }
}

// ---------------- QKV projection + fused RoPE / transpose epilogue ----------------
// blockIdx.y: 0=Q (rope, [B,H,S,D]), 1=K (rope, [B,H,S,D]), 2=V (transposed [B,H,D,S])
__global__ __launch_bounds__(256) void gemm_qkv(
    const u16* xb, const u16* wqb, const u16* wkb, const u16* wvb,
    const float2* tab, u16* Qr, u16* Kr, u16* Vt)
{
  __shared__ __align__(16) u16 ldsA[128 * 64];
  __shared__ __align__(16) u16 ldsB[128 * 64];
  const int bid = blockIdx.x;
  const int m0 = (bid >> 3) * 128;     // 32 m-blocks
  const int n0 = (bid & 7) * 128;      // 8 n-blocks
  const int z = blockIdx.y;
  const u16* W = (z == 0) ? wqb : ((z == 1) ? wkb : wvb);
  f32x4 acc[4][4] = {};
  gemm_core_128(xb, W, DM, m0, n0, ldsA, ldsB, acc);

  const int tid = threadIdx.x, w = tid >> 6, lane = tid & 63;
  const int l15 = lane & 15, g = lane >> 4;
  const int wm = (w >> 1) * 64, wn = (w & 1) * 64;
  u16* dst = (z == 0) ? Qr : Kr;
#pragma unroll
  for (int i = 0; i < 4; ++i) {
#pragma unroll
    for (int j = 0; j < 4; ++j) {
      const int n = n0 + wn + j * 16 + l15;
      const int h = n >> 6, d = n & 63;
#pragma unroll
      for (int r = 0; r < 4; ++r) {
        const int m = m0 + wm + i * 16 + g * 4 + r;
        const int b = m >> 11, s = m & 2047;
        float v = acc[i][j][r];
        if (z < 2) {
          float p = __shfl_xor(v, 1);
          float2 cs = tab[s * 32 + (d >> 1)];
          float o = v * cs.x + ((d & 1) ? p : -p) * cs.y;
          dst[((size_t)(b * NH + h) * S_LEN + s) * DK + d] = f2bf(o);
        } else {
          Vt[((size_t)(b * NH + h) * DK + d) * S_LEN + s] = f2bf(v);
        }
      }
    }
  }
}

// ---------------- output GEMM: out(f32) = ctx * wo^T ----------------
__global__ __launch_bounds__(256) void gemm_out(const u16* ctx, const u16* wob, float* out) {
  __shared__ __align__(16) u16 ldsA[128 * 64];
  __shared__ __align__(16) u16 ldsB[128 * 64];
  const int bid = blockIdx.x;
  const int m0 = (bid >> 3) * 128;
  const int n0 = (bid & 7) * 128;
  f32x4 acc[4][4] = {};
  gemm_core_128(ctx, wob, DM, m0, n0, ldsA, ldsB, acc);

  const int tid = threadIdx.x, w = tid >> 6, lane = tid & 63;
  const int l15 = lane & 15, g = lane >> 4;
  const int wm = (w >> 1) * 64, wn = (w & 1) * 64;
#pragma unroll
  for (int i = 0; i < 4; ++i)
#pragma unroll
    for (int j = 0; j < 4; ++j)
#pragma unroll
      for (int r = 0; r < 4; ++r)
        out[(size_t)(m0 + wm + i * 16 + g * 4 + r) * DM + n0 + wn + j * 16 + l15] = acc[i][j][r];
}

// ---------------- causal flash attention, per-wave 16 q-rows, KV tiles of 32 ----------------
__global__ __launch_bounds__(256) void attn(
    const u16* Qr, const u16* Kr, const u16* Vt, const int* amask, u16* ctx)
{
  __shared__ __align__(16) u16 p_lds[4][16 * 56];   // per-wave P buffer, stride 56 (112B, 16B-aligned)
  const int qb = blockIdx.x;      // q-block (64 rows)
  const int bh = blockIdx.y;      // b*16 + h
  const int b = bh >> 4, h = bh & 15;
  const int tid = threadIdx.x, w = tid >> 6, lane = tid & 63;
  const int l15 = lane & 15, g = lane >> 4;
  const int q0 = qb * 64 + w * 16;                 // this wave's q-row base

  const u16* Qb = Qr + ((size_t)bh * S_LEN + q0) * DK;
  bf16x8 qa0 = *(const bf16x8*)(Qb + l15 * DK + g * 8);
  bf16x8 qa1 = *(const bf16x8*)(Qb + l15 * DK + 32 + g * 8);

  float m_run[4], l_run[4];
  f32x4 o_acc[4];
#pragma unroll
  for (int r = 0; r < 4; ++r) { m_run[r] = -3e38f; l_run[r] = 0.f; }
#pragma unroll
  for (int dt = 0; dt < 4; ++dt) o_acc[dt] = (f32x4){0.f, 0.f, 0.f, 0.f};

  const u16* Kb0 = Kr + (size_t)bh * S_LEN * DK;
  const u16* Vb0 = Vt + (size_t)bh * DK * S_LEN;
  const int kv_end = q0 + 16;                      // keys < kv_end needed (causal)

  for (int kv0 = 0; kv0 < kv_end; kv0 += 32) {
    f32x4 sfrag[2];
    sfrag[0] = (f32x4){0.f, 0.f, 0.f, 0.f};
    sfrag[1] = (f32x4){0.f, 0.f, 0.f, 0.f};
#pragma unroll
    for (int nt = 0; nt < 2; ++nt) {
      const u16* krow = Kb0 + (size_t)(kv0 + nt * 16 + l15) * DK;
      bf16x8 kb0 = *(const bf16x8*)(krow + g * 8);
      bf16x8 kb1 = *(const bf16x8*)(krow + 32 + g * 8);
      sfrag[nt] = __builtin_amdgcn_mfma_f32_16x16x32_bf16(qa0, kb0, sfrag[nt], 0, 0, 0);
      sfrag[nt] = __builtin_amdgcn_mfma_f32_16x16x32_bf16(qa1, kb1, sfrag[nt], 0, 0, 0);
    }
    // mask + scale
    const int kvc0 = kv0 + l15, kvc1 = kv0 + 16 + l15;
    const int pm0 = amask[b * S_LEN + kvc0];
    const int pm1 = amask[b * S_LEN + kvc1];
    float sc[2][4];
#pragma unroll
    for (int r = 0; r < 4; ++r) {
      const int q = q0 + g * 4 + r;
      sc[0][r] = ((kvc0 <= q) && pm0) ? sfrag[0][r] * 0.125f : -1e9f;
      sc[1][r] = ((kvc1 <= q) && pm1) ? sfrag[1][r] * 0.125f : -1e9f;
    }
    // online softmax (row = 16 lanes of the 4-lane-group's quarter)
#pragma unroll
    for (int r = 0; r < 4; ++r) {
      float t = fmaxf(sc[0][r], sc[1][r]);
      t = fmaxf(t, __shfl_xor(t, 1));
      t = fmaxf(t, __shfl_xor(t, 2));
      t = fmaxf(t, __shfl_xor(t, 4));
      t = fmaxf(t, __shfl_xor(t, 8));
      const float mnew = fmaxf(m_run[r], t);
      const float alpha = __expf(m_run[r] - mnew);
      m_run[r] = mnew;
      l_run[r] *= alpha;
#pragma unroll
      for (int dt = 0; dt < 4; ++dt) o_acc[dt][r] *= alpha;
      float p0 = __expf(sc[0][r] - mnew);
      float p1 = __expf(sc[1][r] - mnew);
      p_lds[w][(g * 4 + r) * 56 + l15] = f2bf(p0);
      p_lds[w][(g * 4 + r) * 56 + 16 + l15] = f2bf(p1);
      float ps = p0 + p1;
      ps += __shfl_xor(ps, 1);
      ps += __shfl_xor(ps, 2);
      ps += __shfl_xor(ps, 4);
      ps += __shfl_xor(ps, 8);
      l_run[r] += ps;
    }
    // P as A-fragment (compiler inserts lgkmcnt wait for the LDS RAW)
    bf16x8 pa = *(const bf16x8*)(&p_lds[w][l15 * 56 + g * 8]);
#pragma unroll
    for (int dt = 0; dt < 4; ++dt) {
      bf16x8 vb = *(const bf16x8*)(Vb0 + (size_t)(dt * 16 + l15) * S_LEN + kv0 + g * 8);
      o_acc[dt] = __builtin_amdgcn_mfma_f32_16x16x32_bf16(pa, vb, o_acc[dt], 0, 0, 0);
    }
  }
  // write ctx [B, S, H*D] bf16
#pragma unroll
  for (int dt = 0; dt < 4; ++dt)
#pragma unroll
    for (int r = 0; r < 4; ++r) {
      const int q = q0 + g * 4 + r;
      float v = o_acc[dt][r] / l_run[r];
      ctx[((size_t)(b * S_LEN + q)) * DM + h * DK + dt * 16 + l15] = f2bf(v);
    }
}

extern "C" void kernel_launch(void* const* d_in, const int* in_sizes, int n_in,
                              void* d_out, int out_size, void* d_ws, size_t ws_size,
                              hipStream_t stream) {
  const float* x   = (const float*)d_in[0];
  const int* amask = (const int*)d_in[1];
  const float* wq  = (const float*)d_in[2];
  const float* wk  = (const float*)d_in[3];
  const float* wv  = (const float*)d_in[4];
  const float* wo  = (const float*)d_in[5];
  float* out = (float*)d_out;

  char* ws = (char*)d_ws;
  u16* xb    = (u16*)(ws);                      // 8 MB
  u16* wqb   = (u16*)(ws + ( 8u << 20));        // 2 MB
  u16* wkb   = (u16*)(ws + (10u << 20));
  u16* wvb   = (u16*)(ws + (12u << 20));
  u16* wob   = (u16*)(ws + (14u << 20));
  float2* tab = (float2*)(ws + (16u << 20));    // 512 KB
  u16* Qr    = (u16*)(ws + (17u << 20));        // 8 MB  [B,H,S,D]
  u16* Kr    = (u16*)(ws + (25u << 20));        // 8 MB  [B,H,S,D]
  u16* Vt    = (u16*)(ws + (33u << 20));        // 8 MB  [B,H,D,S]
  u16* ctx   = (u16*)(ws + (41u << 20));        // 8 MB  [B,S,H*D]

  hipLaunchKernelGGL(convert_all, dim3(8192), dim3(256), 0, stream,
                     x, wq, wk, wv, wo, xb, wqb, wkb, wvb, wob);
  hipLaunchKernelGGL(rope_tab_k, dim3(256), dim3(256), 0, stream, tab);
  hipLaunchKernelGGL(gemm_qkv, dim3(256, 3), dim3(256), 0, stream,
                     xb, wqb, wkb, wvb, tab, Qr, Kr, Vt);
  hipLaunchKernelGGL(attn, dim3(32, 32), dim3(256), 0, stream, Qr, Kr, Vt, amask, ctx);
  hipLaunchKernelGGL(gemm_out, dim3(256), dim3(256), 0, stream, ctx, wob, out);
}

// Round 2
// 181.591 us; speedup vs baseline: 1.8866x; 1.8866x over previous
//
#include <hip/hip_runtime.h>
#include <hip/hip_bf16.h>
#include <cstdint>

typedef unsigned short u16;
typedef __bf16 bf16x8 __attribute__((ext_vector_type(8)));
typedef float f32x4 __attribute__((ext_vector_type(4)));

#define S_LEN 2048
#define NH 16
#define DK 64
#define DM 1024
#define M_TOT 4096   // B*S

__device__ __forceinline__ u16 f2bf(float f) {
  union { float f; uint32_t u; } c; c.f = f;
  uint32_t u = c.u;
  u += 0x7fffu + ((u >> 16) & 1u);   // RNE
  return (u16)(u >> 16);
}

__device__ __forceinline__ void gl_lds16(const void* gsrc, void* ldst) {
  __builtin_amdgcn_global_load_lds(
      (const __attribute__((address_space(1))) unsigned int*)gsrc,
      (__attribute__((address_space(3))) unsigned int*)ldst,
      16, 0, 0);
}

#define MFMA16(a, b, c) __builtin_amdgcn_mfma_f32_16x16x32_bf16((a), (b), (c), 0, 0, 0)

// ---------------- fp32 -> bf16 conversion (x + 4 weights) ----------------
__global__ __launch_bounds__(256) void convert_all(
    const float* x, const float* wq, const float* wk, const float* wv, const float* wo,
    u16* xb, u16* wqb, u16* wkb, u16* wvb, u16* wob)
{
  size_t i = ((size_t)blockIdx.x * 256 + threadIdx.x) * 4;
  const float* src; u16* dst; size_t off;
  if (i < 4194304u)      { src = x;  dst = xb;  off = i; }
  else if (i < 5242880u) { src = wq; dst = wqb; off = i - 4194304u; }
  else if (i < 6291456u) { src = wk; dst = wkb; off = i - 5242880u; }
  else if (i < 7340032u) { src = wv; dst = wvb; off = i - 6291456u; }
  else                   { src = wo; dst = wob; off = i - 7340032u; }
  float4 v = *(const float4*)(src + off);
  ushort4 o;
  o.x = f2bf(v.x); o.y = f2bf(v.y); o.z = f2bf(v.z); o.w = f2bf(v.w);
  *(ushort4*)(dst + off) = o;
}

// ---------------- RoPE cos/sin table: tab[pos*32 + i] = {cos, sin} ----------------
__global__ __launch_bounds__(256) void rope_tab_k(float2* tab) {
  int i = blockIdx.x * 256 + threadIdx.x;   // 65536 entries
  int pos = i >> 5, f = i & 31;
  float inv = powf(10000.0f, -(float)f / 32.0f);   // THETA^(-2f/64)
  float ang = (float)pos * inv;
  tab[i] = make_float2(cosf(ang), sinf(ang));
}

// ---------------- shared GEMM core: C(128x128) = A(MxK) * W(NxK)^T, bf16 MFMA ----------------
__device__ __forceinline__ void gemm_core_128(
    const u16* A, const u16* W, int K, int m0, int n0,
    u16* ldsA, u16* ldsB, f32x4 (&acc)[4][4])
{
  const int tid = threadIdx.x;
  const int w = tid >> 6, lane = tid & 63;
  const int l15 = lane & 15, g = lane >> 4;
  const int wm = (w >> 1) * 64, wn = (w & 1) * 64;
  const int lrow = lane >> 3;                              // 0..7 within 8-row chunk
  const int scolb = ((lane & 7) * 16) ^ (lrow << 4);       // pre-swizzled source byte

  for (int kt = 0; kt < K; kt += 64) {
#pragma unroll
    for (int c = 0; c < 4; ++c) {
      const int rb = w * 32 + c * 8;                       // chunk row base (8 rows/chunk)
      const int row = rb + lrow;
      gl_lds16((const char*)(A + (size_t)(m0 + row) * K + kt) + scolb,
               (char*)ldsA + rb * 128);
      gl_lds16((const char*)(W + (size_t)(n0 + row) * K + kt) + scolb,
               (char*)ldsB + rb * 128);
    }
    __syncthreads();
#pragma unroll
    for (int ks = 0; ks < 2; ++ks) {
      bf16x8 af[4], bfr[4];
#pragma unroll
      for (int i = 0; i < 4; ++i) {
        const int ar = wm + i * 16 + l15;
        af[i] = *(const bf16x8*)((const char*)ldsA + ar * 128 +
                                 ((ks * 64 + g * 16) ^ ((ar & 7) << 4)));
        const int br = wn + i * 16 + l15;
        bfr[i] = *(const bf16x8*)((const char*)ldsB + br * 128 +
                                  ((ks * 64 + g * 16) ^ ((br & 7) << 4)));
      }
#pragma unroll
      for (int i = 0; i < 4; ++i)
#pragma unroll
        for (int j = 0; j < 4; ++j)
          acc[i][j] = MFMA16(af[i], bfr[j], acc[i][j]);
    }
    __syncthreads();
  }
}

// ---------------- QKV projection + fused RoPE / transpose epilogue ----------------
__global__ __launch_bounds__(256) void gemm_qkv(
    const u16* xb, const u16* wqb, const u16* wkb, const u16* wvb,
    const float2* tab, u16* Qr, u16* Kr, u16* Vt)
{
  __shared__ __align__(16) u16 ldsA[128 * 64];
  __shared__ __align__(16) u16 ldsB[128 * 64];
  const int bid = blockIdx.x;
  const int m0 = (bid >> 3) * 128;     // 32 m-blocks
  const int n0 = (bid & 7) * 128;      // 8 n-blocks
  const int z = blockIdx.y;
  const u16* W = (z == 0) ? wqb : ((z == 1) ? wkb : wvb);
  f32x4 acc[4][4] = {};
  gemm_core_128(xb, W, DM, m0, n0, ldsA, ldsB, acc);

  const int tid = threadIdx.x, w = tid >> 6, lane = tid & 63;
  const int l15 = lane & 15, g = lane >> 4;
  const int wm = (w >> 1) * 64, wn = (w & 1) * 64;
  u16* dst = (z == 0) ? Qr : Kr;
#pragma unroll
  for (int i = 0; i < 4; ++i) {
#pragma unroll
    for (int j = 0; j < 4; ++j) {
      const int n = n0 + wn + j * 16 + l15;
      const int h = n >> 6, d = n & 63;
#pragma unroll
      for (int r = 0; r < 4; ++r) {
        const int m = m0 + wm + i * 16 + g * 4 + r;
        const int b = m >> 11, s = m & 2047;
        float v = acc[i][j][r];
        if (z < 2) {
          float p = __shfl_xor(v, 1);
          float2 cs = tab[s * 32 + (d >> 1)];
          float o = v * cs.x + ((d & 1) ? p : -p) * cs.y;
          dst[((size_t)(b * NH + h) * S_LEN + s) * DK + d] = f2bf(o);
        } else {
          Vt[((size_t)(b * NH + h) * DK + d) * S_LEN + s] = f2bf(v);
        }
      }
    }
  }
}

// ---------------- output GEMM: out(f32) = ctx * wo^T ----------------
__global__ __launch_bounds__(256) void gemm_out(const u16* ctx, const u16* wob, float* out) {
  __shared__ __align__(16) u16 ldsA[128 * 64];
  __shared__ __align__(16) u16 ldsB[128 * 64];
  const int bid = blockIdx.x;
  const int m0 = (bid >> 3) * 128;
  const int n0 = (bid & 7) * 128;
  f32x4 acc[4][4] = {};
  gemm_core_128(ctx, wob, DM, m0, n0, ldsA, ldsB, acc);

  const int tid = threadIdx.x, w = tid >> 6, lane = tid & 63;
  const int l15 = lane & 15, g = lane >> 4;
  const int wm = (w >> 1) * 64, wn = (w & 1) * 64;
#pragma unroll
  for (int i = 0; i < 4; ++i)
#pragma unroll
    for (int j = 0; j < 4; ++j)
#pragma unroll
      for (int r = 0; r < 4; ++r)
        out[(size_t)(m0 + wm + i * 16 + g * 4 + r) * DM + n0 + wn + j * 16 + l15] = acc[i][j][r];
}

// ---------------- causal flash attention v2 ----------------
// Balanced pairing: block ip handles q-chunks {ip, 31-ip} (64 rows each, 4 waves x 16 rows).
// K/V tiles (64 kv) staged in LDS (swizzled, double-buffered), shared by all waves AND both chunks.
__global__ __launch_bounds__(256) void attn2(
    const u16* Qr, const u16* Kr, const u16* Vt, const int* amask, u16* ctx)
{
  __shared__ __align__(16) u16 ldsK[2][64 * 64];
  __shared__ __align__(16) u16 ldsV[2][64 * 64];
  __shared__ __align__(16) u16 plds[2][4][16 * 72];   // stride 72 elems = 144B: 16B-aligned, 2-way only

  const int ip = blockIdx.x;          // 0..15
  const int bh = blockIdx.y;
  const int b = bh >> 4, h = bh & 15;
  const int qcA = ip, qcB = 31 - ip;
  const int tid = threadIdx.x, w = tid >> 6, lane = tid & 63;
  const int l15 = lane & 15, g = lane >> 4;
  const int r8 = lane >> 3;
  const int sw = ((lane & 7) * 16) ^ (r8 << 4);       // pre-swizzled source byte (rule #21)

  const u16* Kb0 = Kr + (size_t)bh * S_LEN * DK;
  const u16* Vb0 = Vt + (size_t)bh * DK * S_LEN;
  const u16* Qb  = Qr + (size_t)bh * S_LEN * DK;

  const int qA0 = qcA * 64 + w * 16;
  const int qB0 = qcB * 64 + w * 16;
  bf16x8 qaA[2], qaB[2];
  qaA[0] = *(const bf16x8*)(Qb + (size_t)(qA0 + l15) * DK + g * 8);
  qaA[1] = *(const bf16x8*)(Qb + (size_t)(qA0 + l15) * DK + 32 + g * 8);
  qaB[0] = *(const bf16x8*)(Qb + (size_t)(qB0 + l15) * DK + g * 8);
  qaB[1] = *(const bf16x8*)(Qb + (size_t)(qB0 + l15) * DK + 32 + g * 8);

  float mA[4], lA[4], mB[4], lB[4];
  f32x4 oA[4], oB[4];
#pragma unroll
  for (int r = 0; r < 4; ++r) { mA[r] = mB[r] = -3e38f; lA[r] = lB[r] = 0.f; }
#pragma unroll
  for (int dt = 0; dt < 4; ++dt) {
    oA[dt] = (f32x4){0.f, 0.f, 0.f, 0.f};
    oB[dt] = (f32x4){0.f, 0.f, 0.f, 0.f};
  }

  auto stage = [&](int buf, int t) {
    const size_t kv0 = (size_t)t * 64;
#pragma unroll
    for (int c = 0; c < 2; ++c) {
      const int rb = c * 32 + w * 8;                  // wave-uniform row base (8 rows/instr)
      const int row = rb + r8;
      gl_lds16((const char*)(Kb0 + (kv0 + row) * DK) + sw,
               (char*)&ldsK[buf][0] + rb * 128);
      gl_lds16((const char*)(Vb0 + (size_t)row * S_LEN + kv0) + sw,
               (char*)&ldsV[buf][0] + rb * 128);
    }
  };

  stage(0, 0);
  const int ntB = qcB + 1;
  int cur = 0;
  __syncthreads();

  for (int t = 0; t < ntB; ++t) {
    if (t + 1 < ntB) stage(cur ^ 1, t + 1);
    const int kv0 = t * 64;
    int pm[4];
#pragma unroll
    for (int nt = 0; nt < 4; ++nt) pm[nt] = amask[b * S_LEN + kv0 + nt * 16 + l15];

    bf16x8 kb[4][2];
#pragma unroll
    for (int nt = 0; nt < 4; ++nt) {
      const int row = nt * 16 + l15;
#pragma unroll
      for (int ks = 0; ks < 2; ++ks)
        kb[nt][ks] = *(const bf16x8*)((const char*)&ldsK[cur][0] + row * 128 +
                                      ((ks * 64 + g * 16) ^ ((row & 7) << 4)));
    }
    const bool actA = (t <= qcA);
    f32x4 sA[4], sB[4];
#pragma unroll
    for (int nt = 0; nt < 4; ++nt) {
      sA[nt] = (f32x4){0.f, 0.f, 0.f, 0.f};
      sB[nt] = (f32x4){0.f, 0.f, 0.f, 0.f};
    }
    __builtin_amdgcn_s_setprio(1);
    if (actA) {
#pragma unroll
      for (int nt = 0; nt < 4; ++nt) {
        sA[nt] = MFMA16(qaA[0], kb[nt][0], sA[nt]);
        sA[nt] = MFMA16(qaA[1], kb[nt][1], sA[nt]);
      }
    }
#pragma unroll
    for (int nt = 0; nt < 4; ++nt) {
      sB[nt] = MFMA16(qaB[0], kb[nt][0], sB[nt]);
      sB[nt] = MFMA16(qaB[1], kb[nt][1], sB[nt]);
    }
    __builtin_amdgcn_s_setprio(0);

    bf16x8 vb[4][2];
#pragma unroll
    for (int dt = 0; dt < 4; ++dt) {
      const int row = dt * 16 + l15;
#pragma unroll
      for (int ks = 0; ks < 2; ++ks)
        vb[dt][ks] = *(const bf16x8*)((const char*)&ldsV[cur][0] + row * 128 +
                                      ((ks * 64 + g * 16) ^ ((row & 7) << 4)));
    }

    auto softmax_pv = [&](f32x4 (&s)[4], float (&m)[4], float (&l)[4], f32x4 (&o)[4],
                          int q0, bool diag, int pbuf) {
      u16* pw = &plds[pbuf][w][0];
#pragma unroll
      for (int nt = 0; nt < 4; ++nt) {
        const int kvc = kv0 + nt * 16 + l15;
#pragma unroll
        for (int r = 0; r < 4; ++r) {
          const bool ok = pm[nt] && (!diag || kvc <= q0 + g * 4 + r);
          s[nt][r] = ok ? s[nt][r] * 0.125f : -1e9f;
        }
      }
#pragma unroll
      for (int r = 0; r < 4; ++r) {
        float t0 = fmaxf(fmaxf(s[0][r], s[1][r]), fmaxf(s[2][r], s[3][r]));
        t0 = fmaxf(t0, __shfl_xor(t0, 1));
        t0 = fmaxf(t0, __shfl_xor(t0, 2));
        t0 = fmaxf(t0, __shfl_xor(t0, 4));
        t0 = fmaxf(t0, __shfl_xor(t0, 8));
        const float mnew = fmaxf(m[r], t0);
        const float alpha = __expf(m[r] - mnew);
        m[r] = mnew;
        l[r] *= alpha;
#pragma unroll
        for (int dt = 0; dt < 4; ++dt) o[dt][r] *= alpha;
        float ps = 0.f;
#pragma unroll
        for (int nt = 0; nt < 4; ++nt) {
          const float p = __expf(s[nt][r] - mnew);
          ps += p;
          pw[(g * 4 + r) * 72 + nt * 16 + l15] = f2bf(p);
        }
        ps += __shfl_xor(ps, 1);
        ps += __shfl_xor(ps, 2);
        ps += __shfl_xor(ps, 4);
        ps += __shfl_xor(ps, 8);
        l[r] += ps;
      }
      bf16x8 pa0 = *(const bf16x8*)(pw + l15 * 72 + g * 8);
      bf16x8 pa1 = *(const bf16x8*)(pw + l15 * 72 + 32 + g * 8);
      __builtin_amdgcn_s_setprio(1);
#pragma unroll
      for (int dt = 0; dt < 4; ++dt) {
        o[dt] = MFMA16(pa0, vb[dt][0], o[dt]);
        o[dt] = MFMA16(pa1, vb[dt][1], o[dt]);
      }
      __builtin_amdgcn_s_setprio(0);
    };
    if (actA) softmax_pv(sA, mA, lA, oA, qA0, t == qcA, 0);
    softmax_pv(sB, mB, lB, oB, qB0, t == qcB, 1);

    __syncthreads();
    cur ^= 1;
  }

  auto wr = [&](float (&l)[4], f32x4 (&o)[4], int q0) {
#pragma unroll
    for (int dt = 0; dt < 4; ++dt)
#pragma unroll
      for (int r = 0; r < 4; ++r) {
        const int q = q0 + g * 4 + r;
        ctx[((size_t)(b * S_LEN + q)) * DM + h * DK + dt * 16 + l15] = f2bf(o[dt][r] / l[r]);
      }
  };
  wr(lA, oA, qA0);
  wr(lB, oB, qB0);
}

extern "C" void kernel_launch(void* const* d_in, const int* in_sizes, int n_in,
                              void* d_out, int out_size, void* d_ws, size_t ws_size,
                              hipStream_t stream) {
  const float* x   = (const float*)d_in[0];
  const int* amask = (const int*)d_in[1];
  const float* wq  = (const float*)d_in[2];
  const float* wk  = (const float*)d_in[3];
  const float* wv  = (const float*)d_in[4];
  const float* wo  = (const float*)d_in[5];
  float* out = (float*)d_out;

  char* ws = (char*)d_ws;
  u16* xb    = (u16*)(ws);                      // 8 MB
  u16* wqb   = (u16*)(ws + ( 8u << 20));        // 2 MB
  u16* wkb   = (u16*)(ws + (10u << 20));
  u16* wvb   = (u16*)(ws + (12u << 20));
  u16* wob   = (u16*)(ws + (14u << 20));
  float2* tab = (float2*)(ws + (16u << 20));    // 512 KB
  u16* Qr    = (u16*)(ws + (17u << 20));        // 8 MB  [B,H,S,D]
  u16* Kr    = (u16*)(ws + (25u << 20));        // 8 MB  [B,H,S,D]
  u16* Vt    = (u16*)(ws + (33u << 20));        // 8 MB  [B,H,D,S]
  u16* ctx   = (u16*)(ws + (41u << 20));        // 8 MB  [B,S,H*D]

  hipLaunchKernelGGL(convert_all, dim3(8192), dim3(256), 0, stream,
                     x, wq, wk, wv, wo, xb, wqb, wkb, wvb, wob);
  hipLaunchKernelGGL(rope_tab_k, dim3(256), dim3(256), 0, stream, tab);
  hipLaunchKernelGGL(gemm_qkv, dim3(256, 3), dim3(256), 0, stream,
                     xb, wqb, wkb, wvb, tab, Qr, Kr, Vt);
  hipLaunchKernelGGL(attn2, dim3(16, 32), dim3(256), 0, stream, Qr, Kr, Vt, amask, ctx);
  hipLaunchKernelGGL(gemm_out, dim3(256), dim3(256), 0, stream, ctx, wob, out);
}

// Round 3
// 162.113 us; speedup vs baseline: 2.1133x; 1.1202x over previous
//
#include <hip/hip_runtime.h>
#include <hip/hip_bf16.h>
#include <cstdint>

typedef unsigned short u16;
typedef __bf16 bf16x8 __attribute__((ext_vector_type(8)));
typedef float f32x4 __attribute__((ext_vector_type(4)));

#define S_LEN 2048
#define NH 16
#define DK 64
#define DM 1024
#define M_TOT 4096   // B*S

__device__ __forceinline__ u16 f2bf(float f) {
  union { float f; uint32_t u; } c; c.f = f;
  uint32_t u = c.u;
  u += 0x7fffu + ((u >> 16) & 1u);   // RNE
  return (u16)(u >> 16);
}

__device__ __forceinline__ void gl_lds16(const void* gsrc, void* ldst) {
  __builtin_amdgcn_global_load_lds(
      (const __attribute__((address_space(1))) unsigned int*)gsrc,
      (__attribute__((address_space(3))) unsigned int*)ldst,
      16, 0, 0);
}

#define MFMA16(a, b, c) __builtin_amdgcn_mfma_f32_16x16x32_bf16((a), (b), (c), 0, 0, 0)

// ---------------- fp32 -> bf16 conversion (x + 4 weights) ----------------
__global__ __launch_bounds__(256) void convert_all(
    const float* x, const float* wq, const float* wk, const float* wv, const float* wo,
    u16* xb, u16* wqb, u16* wkb, u16* wvb, u16* wob)
{
  size_t i = ((size_t)blockIdx.x * 256 + threadIdx.x) * 4;
  const float* src; u16* dst; size_t off;
  if (i < 4194304u)      { src = x;  dst = xb;  off = i; }
  else if (i < 5242880u) { src = wq; dst = wqb; off = i - 4194304u; }
  else if (i < 6291456u) { src = wk; dst = wkb; off = i - 5242880u; }
  else if (i < 7340032u) { src = wv; dst = wvb; off = i - 6291456u; }
  else                   { src = wo; dst = wob; off = i - 7340032u; }
  float4 v = *(const float4*)(src + off);
  ushort4 o;
  o.x = f2bf(v.x); o.y = f2bf(v.y); o.z = f2bf(v.z); o.w = f2bf(v.w);
  *(ushort4*)(dst + off) = o;
}

// ---------------- RoPE cos/sin table: tab[pos*32 + i] = {cos, sin} ----------------
__global__ __launch_bounds__(256) void rope_tab_k(float2* tab) {
  int i = blockIdx.x * 256 + threadIdx.x;   // 65536 entries
  int pos = i >> 5, f = i & 31;
  float inv = powf(10000.0f, -(float)f / 32.0f);   // THETA^(-2f/64)
  float ang = (float)pos * inv;
  tab[i] = make_float2(cosf(ang), sinf(ang));
}

// ---------------- shared GEMM core (double-buffered prefetch) ----------------
// C(128x128) = A(MxK) * W(NxK)^T, bf16 MFMA. LDS XOR-swizzled (rule #21:
// linear gl_lds dest + pre-swizzled global source + swizzled ds_read).
// Prefetch tile t+1 BEFORE computing tile t; __syncthreads' vmcnt(0) drain
// lands after ~350cyc of MFMA+ds_read, hiding most of the load latency.
__device__ __forceinline__ void gemm_core_128_db(
    const u16* A, const u16* W, int K, int m0, int n0,
    u16 (&ldsA)[2][128 * 64], u16 (&ldsB)[2][128 * 64], f32x4 (&acc)[4][4])
{
  const int tid = threadIdx.x;
  const int w = tid >> 6, lane = tid & 63;
  const int l15 = lane & 15, g = lane >> 4;
  const int wm = (w >> 1) * 64, wn = (w & 1) * 64;
  const int lrow = lane >> 3;                              // 0..7 within 8-row chunk
  const int scolb = ((lane & 7) * 16) ^ (lrow << 4);       // pre-swizzled source byte

  auto stage = [&](int buf, int kt) {
#pragma unroll
    for (int c = 0; c < 4; ++c) {
      const int rb = w * 32 + c * 8;                       // chunk row base (8 rows/instr)
      const int row = rb + lrow;
      gl_lds16((const char*)(A + (size_t)(m0 + row) * K + kt) + scolb,
               (char*)&ldsA[buf][0] + rb * 128);
      gl_lds16((const char*)(W + (size_t)(n0 + row) * K + kt) + scolb,
               (char*)&ldsB[buf][0] + rb * 128);
    }
  };

  stage(0, 0);
  __syncthreads();
  int cur = 0;
  for (int kt = 0; kt < K; kt += 64) {
    if (kt + 64 < K) stage(cur ^ 1, kt + 64);
#pragma unroll
    for (int ks = 0; ks < 2; ++ks) {
      bf16x8 af[4], bfr[4];
#pragma unroll
      for (int i = 0; i < 4; ++i) {
        const int ar = wm + i * 16 + l15;
        af[i] = *(const bf16x8*)((const char*)&ldsA[cur][0] + ar * 128 +
                                 ((ks * 64 + g * 16) ^ ((ar & 7) << 4)));
        const int br = wn + i * 16 + l15;
        bfr[i] = *(const bf16x8*)((const char*)&ldsB[cur][0] + br * 128 +
                                  ((ks * 64 + g * 16) ^ ((br & 7) << 4)));
      }
#pragma unroll
      for (int i = 0; i < 4; ++i)
#pragma unroll
        for (int j = 0; j < 4; ++j)
          acc[i][j] = MFMA16(af[i], bfr[j], acc[i][j]);
    }
    __syncthreads();
    cur ^= 1;
  }
}

// XCD-aware bijective block mapping: 256 blocks -> (m_idx 0..31, n_idx 0..7).
// Each XCD owns 4 consecutive m-panels (1MB A, L2-fit) x all 8 n-panels (2MB).
__device__ __forceinline__ void xcd_map(int bid, int& m0, int& n0) {
  const int xcd = bid & 7, v = bid >> 3;
  m0 = (xcd * 4 + (v >> 3)) * 128;
  n0 = (v & 7) * 128;
}

// ---------------- QKV projection + fused RoPE / transpose epilogue ----------------
__global__ __launch_bounds__(256) void gemm_qkv(
    const u16* xb, const u16* wqb, const u16* wkb, const u16* wvb,
    const float2* tab, u16* Qr, u16* Kr, u16* Vt)
{
  __shared__ __align__(16) u16 ldsA[2][128 * 64];
  __shared__ __align__(16) u16 ldsB[2][128 * 64];
  int m0, n0;
  xcd_map(blockIdx.x, m0, n0);
  const int z = blockIdx.y;
  const u16* W = (z == 0) ? wqb : ((z == 1) ? wkb : wvb);
  f32x4 acc[4][4] = {};
  gemm_core_128_db(xb, W, DM, m0, n0, ldsA, ldsB, acc);

  const int tid = threadIdx.x, w = tid >> 6, lane = tid & 63;
  const int l15 = lane & 15, g = lane >> 4;
  const int wm = (w >> 1) * 64, wn = (w & 1) * 64;
  u16* dst = (z == 0) ? Qr : Kr;
#pragma unroll
  for (int i = 0; i < 4; ++i) {
#pragma unroll
    for (int j = 0; j < 4; ++j) {
      const int n = n0 + wn + j * 16 + l15;
      const int h = n >> 6, d = n & 63;
#pragma unroll
      for (int r = 0; r < 4; ++r) {
        const int m = m0 + wm + i * 16 + g * 4 + r;
        const int b = m >> 11, s = m & 2047;
        float v = acc[i][j][r];
        if (z < 2) {
          float p = __shfl_xor(v, 1);
          float2 cs = tab[s * 32 + (d >> 1)];
          float o = v * cs.x + ((d & 1) ? p : -p) * cs.y;
          if (z == 0) o *= 0.125f;            // fold 1/sqrt(DK) into Q
          dst[((size_t)(b * NH + h) * S_LEN + s) * DK + d] = f2bf(o);
        } else {
          Vt[((size_t)(b * NH + h) * DK + d) * S_LEN + s] = f2bf(v);
        }
      }
    }
  }
}

// ---------------- output GEMM: out(f32) = ctx * wo^T ----------------
__global__ __launch_bounds__(256) void gemm_out(const u16* ctx, const u16* wob, float* out) {
  __shared__ __align__(16) u16 ldsA[2][128 * 64];
  __shared__ __align__(16) u16 ldsB[2][128 * 64];
  int m0, n0;
  xcd_map(blockIdx.x, m0, n0);
  f32x4 acc[4][4] = {};
  gemm_core_128_db(ctx, wob, DM, m0, n0, ldsA, ldsB, acc);

  const int tid = threadIdx.x, w = tid >> 6, lane = tid & 63;
  const int l15 = lane & 15, g = lane >> 4;
  const int wm = (w >> 1) * 64, wn = (w & 1) * 64;
#pragma unroll
  for (int i = 0; i < 4; ++i)
#pragma unroll
    for (int j = 0; j < 4; ++j)
#pragma unroll
      for (int r = 0; r < 4; ++r)
        out[(size_t)(m0 + wm + i * 16 + g * 4 + r) * DM + n0 + wn + j * 16 + l15] = acc[i][j][r];
}

// ---------------- causal flash attention v3 ----------------
// Balanced pairing: block ip handles q-chunks {ip, 31-ip} (64 rows, 4 waves x 16).
// K/V 64-kv tiles staged in LDS (swizzled, double-buffered, prefetched).
// Softmax: Q pre-scaled; row-sum via ones-MFMA; T13 defer-max (THR=8).
__global__ __launch_bounds__(256) void attn3(
    const u16* Qr, const u16* Kr, const u16* Vt, const int* amask, u16* ctx)
{
  __shared__ __align__(16) u16 ldsK[2][64 * 64];
  __shared__ __align__(16) u16 ldsV[2][64 * 64];
  __shared__ __align__(16) u16 plds[4][16 * 72];   // per-wave P buffer

  const int ip = blockIdx.x;          // 0..15
  const int bh = blockIdx.y;
  const int b = bh >> 4, h = bh & 15;
  const int qcA = ip, qcB = 31 - ip;
  const int tid = threadIdx.x, w = tid >> 6, lane = tid & 63;
  const int l15 = lane & 15, g = lane >> 4;
  const int r8 = lane >> 3;
  const int sw = ((lane & 7) * 16) ^ (r8 << 4);    // pre-swizzled source byte

  const u16* Kb0 = Kr + (size_t)bh * S_LEN * DK;
  const u16* Vb0 = Vt + (size_t)bh * DK * S_LEN;
  const u16* Qb  = Qr + (size_t)bh * S_LEN * DK;

  const int qA0 = qcA * 64 + w * 16;
  const int qB0 = qcB * 64 + w * 16;
  bf16x8 qaA[2], qaB[2];
  qaA[0] = *(const bf16x8*)(Qb + (size_t)(qA0 + l15) * DK + g * 8);
  qaA[1] = *(const bf16x8*)(Qb + (size_t)(qA0 + l15) * DK + 32 + g * 8);
  qaB[0] = *(const bf16x8*)(Qb + (size_t)(qB0 + l15) * DK + g * 8);
  qaB[1] = *(const bf16x8*)(Qb + (size_t)(qB0 + l15) * DK + 32 + g * 8);

  union { u16 u[8]; bf16x8 v; } one_u;
#pragma unroll
  for (int i = 0; i < 8; ++i) one_u.u[i] = 0x3F80;   // bf16 1.0
  const bf16x8 ones = one_u.v;

  float mA[4], mB[4];
  f32x4 lA = {0.f, 0.f, 0.f, 0.f}, lB = {0.f, 0.f, 0.f, 0.f};
  f32x4 oA[4], oB[4];
#pragma unroll
  for (int r = 0; r < 4; ++r) { mA[r] = mB[r] = -3e38f; }
#pragma unroll
  for (int dt = 0; dt < 4; ++dt) {
    oA[dt] = (f32x4){0.f, 0.f, 0.f, 0.f};
    oB[dt] = (f32x4){0.f, 0.f, 0.f, 0.f};
  }

  auto stage = [&](int buf, int t) {
    const size_t kv0 = (size_t)t * 64;
#pragma unroll
    for (int c = 0; c < 2; ++c) {
      const int rb = c * 32 + w * 8;
      const int row = rb + r8;
      gl_lds16((const char*)(Kb0 + (kv0 + row) * DK) + sw,
               (char*)&ldsK[buf][0] + rb * 128);
      gl_lds16((const char*)(Vb0 + (size_t)row * S_LEN + kv0) + sw,
               (char*)&ldsV[buf][0] + rb * 128);
    }
  };

  stage(0, 0);
  const int ntB = qcB + 1;
  int cur = 0;
  __syncthreads();

  for (int t = 0; t < ntB; ++t) {
    if (t + 1 < ntB) stage(cur ^ 1, t + 1);
    const int kv0 = t * 64;
    int pm[4];
#pragma unroll
    for (int nt = 0; nt < 4; ++nt) pm[nt] = amask[b * S_LEN + kv0 + nt * 16 + l15];

    bf16x8 kb[4][2];
#pragma unroll
    for (int nt = 0; nt < 4; ++nt) {
      const int row = nt * 16 + l15;
#pragma unroll
      for (int ks = 0; ks < 2; ++ks)
        kb[nt][ks] = *(const bf16x8*)((const char*)&ldsK[cur][0] + row * 128 +
                                      ((ks * 64 + g * 16) ^ ((row & 7) << 4)));
    }
    const bool actA = (t <= qcA);
    f32x4 sA[4], sB[4];
#pragma unroll
    for (int nt = 0; nt < 4; ++nt) {
      sA[nt] = (f32x4){0.f, 0.f, 0.f, 0.f};
      sB[nt] = (f32x4){0.f, 0.f, 0.f, 0.f};
    }
    __builtin_amdgcn_s_setprio(1);
    if (actA) {
#pragma unroll
      for (int nt = 0; nt < 4; ++nt) {
        sA[nt] = MFMA16(qaA[0], kb[nt][0], sA[nt]);
        sA[nt] = MFMA16(qaA[1], kb[nt][1], sA[nt]);
      }
    }
#pragma unroll
    for (int nt = 0; nt < 4; ++nt) {
      sB[nt] = MFMA16(qaB[0], kb[nt][0], sB[nt]);
      sB[nt] = MFMA16(qaB[1], kb[nt][1], sB[nt]);
    }
    __builtin_amdgcn_s_setprio(0);

    bf16x8 vb[4][2];
#pragma unroll
    for (int dt = 0; dt < 4; ++dt) {
      const int row = dt * 16 + l15;
#pragma unroll
      for (int ks = 0; ks < 2; ++ks)
        vb[dt][ks] = *(const bf16x8*)((const char*)&ldsV[cur][0] + row * 128 +
                                      ((ks * 64 + g * 16) ^ ((row & 7) << 4)));
    }

    auto softmax_pv = [&](f32x4 (&s)[4], float (&m)[4], f32x4& lacc, f32x4 (&o)[4],
                          int q0, bool diag) {
      u16* pw = &plds[w][0];
#pragma unroll
      for (int nt = 0; nt < 4; ++nt) {
        const int kvc = kv0 + nt * 16 + l15;
#pragma unroll
        for (int r = 0; r < 4; ++r) {
          const bool ok = pm[nt] && (!diag || kvc <= q0 + g * 4 + r);
          s[nt][r] = ok ? s[nt][r] : -1e9f;
        }
      }
      float tmax[4];
      bool need = false;
#pragma unroll
      for (int r = 0; r < 4; ++r) {
        float t0 = fmaxf(fmaxf(s[0][r], s[1][r]), fmaxf(s[2][r], s[3][r]));
        t0 = fmaxf(t0, __shfl_xor(t0, 1));
        t0 = fmaxf(t0, __shfl_xor(t0, 2));
        t0 = fmaxf(t0, __shfl_xor(t0, 4));
        t0 = fmaxf(t0, __shfl_xor(t0, 8));
        tmax[r] = t0;
        need = need || (t0 > m[r] + 8.f);
      }
      if (__any((int)need)) {                      // T13: rescale only on growth
#pragma unroll
        for (int r = 0; r < 4; ++r) {
          const float mnew = fmaxf(m[r], tmax[r]);
          const float alpha = __expf(m[r] - mnew);
          m[r] = mnew;
          lacc[r] *= alpha;
#pragma unroll
          for (int dt = 0; dt < 4; ++dt) o[dt][r] *= alpha;
        }
      }
#pragma unroll
      for (int r = 0; r < 4; ++r) {
#pragma unroll
        for (int nt = 0; nt < 4; ++nt)
          pw[(g * 4 + r) * 72 + nt * 16 + l15] = f2bf(__expf(s[nt][r] - m[r]));
      }
      bf16x8 pa0 = *(const bf16x8*)(pw + l15 * 72 + g * 8);
      bf16x8 pa1 = *(const bf16x8*)(pw + l15 * 72 + 32 + g * 8);
      __builtin_amdgcn_s_setprio(1);
      lacc = MFMA16(pa0, ones, lacc);              // row-sum: l += P . 1
      lacc = MFMA16(pa1, ones, lacc);
#pragma unroll
      for (int dt = 0; dt < 4; ++dt) {
        o[dt] = MFMA16(pa0, vb[dt][0], o[dt]);
        o[dt] = MFMA16(pa1, vb[dt][1], o[dt]);
      }
      __builtin_amdgcn_s_setprio(0);
    };
    if (actA) softmax_pv(sA, mA, lA, oA, qA0, t == qcA);
    softmax_pv(sB, mB, lB, oB, qB0, t == qcB);

    __syncthreads();
    cur ^= 1;
  }

  auto wr = [&](f32x4& lacc, f32x4 (&o)[4], int q0) {
#pragma unroll
    for (int dt = 0; dt < 4; ++dt)
#pragma unroll
      for (int r = 0; r < 4; ++r) {
        const int q = q0 + g * 4 + r;
        ctx[((size_t)(b * S_LEN + q)) * DM + h * DK + dt * 16 + l15] =
            f2bf(o[dt][r] / lacc[r]);
      }
  };
  wr(lA, oA, qA0);
  wr(lB, oB, qB0);
}

extern "C" void kernel_launch(void* const* d_in, const int* in_sizes, int n_in,
                              void* d_out, int out_size, void* d_ws, size_t ws_size,
                              hipStream_t stream) {
  const float* x   = (const float*)d_in[0];
  const int* amask = (const int*)d_in[1];
  const float* wq  = (const float*)d_in[2];
  const float* wk  = (const float*)d_in[3];
  const float* wv  = (const float*)d_in[4];
  const float* wo  = (const float*)d_in[5];
  float* out = (float*)d_out;

  char* ws = (char*)d_ws;
  u16* xb    = (u16*)(ws);                      // 8 MB
  u16* wqb   = (u16*)(ws + ( 8u << 20));        // 2 MB
  u16* wkb   = (u16*)(ws + (10u << 20));
  u16* wvb   = (u16*)(ws + (12u << 20));
  u16* wob   = (u16*)(ws + (14u << 20));
  float2* tab = (float2*)(ws + (16u << 20));    // 512 KB
  u16* Qr    = (u16*)(ws + (17u << 20));        // 8 MB  [B,H,S,D]
  u16* Kr    = (u16*)(ws + (25u << 20));        // 8 MB  [B,H,S,D]
  u16* Vt    = (u16*)(ws + (33u << 20));        // 8 MB  [B,H,D,S]
  u16* ctx   = (u16*)(ws + (41u << 20));        // 8 MB  [B,S,H*D]

  hipLaunchKernelGGL(convert_all, dim3(8192), dim3(256), 0, stream,
                     x, wq, wk, wv, wo, xb, wqb, wkb, wvb, wob);
  hipLaunchKernelGGL(rope_tab_k, dim3(256), dim3(256), 0, stream, tab);
  hipLaunchKernelGGL(gemm_qkv, dim3(256, 3), dim3(256), 0, stream,
                     xb, wqb, wkb, wvb, tab, Qr, Kr, Vt);
  hipLaunchKernelGGL(attn3, dim3(16, 32), dim3(256), 0, stream, Qr, Kr, Vt, amask, ctx);
  hipLaunchKernelGGL(gemm_out, dim3(256), dim3(256), 0, stream, ctx, wob, out);
}

// Round 4
// 159.040 us; speedup vs baseline: 2.1541x; 1.0193x over previous
//
#include <hip/hip_runtime.h>
#include <hip/hip_bf16.h>
#include <cstdint>

typedef unsigned short u16;
typedef __bf16 bf16x8 __attribute__((ext_vector_type(8)));
typedef float f32x4 __attribute__((ext_vector_type(4)));

#define S_LEN 2048
#define NH 16
#define DK 64
#define DM 1024

__device__ __forceinline__ u16 f2bf(float f) {
  union { float f; uint32_t u; } c; c.f = f;
  uint32_t u = c.u;
  u += 0x7fffu + ((u >> 16) & 1u);   // RNE
  return (u16)(u >> 16);
}

__device__ __forceinline__ void gl_lds16(const void* gsrc, void* ldst) {
  __builtin_amdgcn_global_load_lds(
      (const __attribute__((address_space(1))) unsigned int*)gsrc,
      (__attribute__((address_space(3))) unsigned int*)ldst,
      16, 0, 0);
}

#define MFMA16(a, b, c) __builtin_amdgcn_mfma_f32_16x16x32_bf16((a), (b), (c), 0, 0, 0)
#define VMW(N) asm volatile("s_waitcnt vmcnt(" #N ")" ::: "memory")
#define BAR() __builtin_amdgcn_s_barrier()

// ---------------- fp32 -> bf16 conversion (x + 4 weights) ----------------
__global__ __launch_bounds__(256) void convert_all(
    const float* x, const float* wq, const float* wk, const float* wv, const float* wo,
    u16* xb, u16* wqb, u16* wkb, u16* wvb, u16* wob)
{
  size_t i = ((size_t)blockIdx.x * 256 + threadIdx.x) * 4;
  const float* src; u16* dst; size_t off;
  if (i < 4194304u)      { src = x;  dst = xb;  off = i; }
  else if (i < 5242880u) { src = wq; dst = wqb; off = i - 4194304u; }
  else if (i < 6291456u) { src = wk; dst = wkb; off = i - 5242880u; }
  else if (i < 7340032u) { src = wv; dst = wvb; off = i - 6291456u; }
  else                   { src = wo; dst = wob; off = i - 7340032u; }
  float4 v = *(const float4*)(src + off);
  ushort4 o;
  o.x = f2bf(v.x); o.y = f2bf(v.y); o.z = f2bf(v.z); o.w = f2bf(v.w);
  *(ushort4*)(dst + off) = o;
}

// ---------------- RoPE cos/sin table ----------------
__global__ __launch_bounds__(256) void rope_tab_k(float2* tab) {
  int i = blockIdx.x * 256 + threadIdx.x;   // 65536 entries
  int pos = i >> 5, f = i & 31;
  float inv = powf(10000.0f, -(float)f / 32.0f);
  float ang = (float)pos * inv;
  tab[i] = make_float2(cosf(ang), sinf(ang));
}

// ================= fused QKV: 256x256 tile, 8 waves, 4-phase counted-vmcnt =================
// W = concat(wq,wk,wv): grid 16 m-tiles x 12 n-tiles. BK=64, 16 K-tiles.
// LDS: [buf][A/B][half][128x64] bf16 = 128 KB. Halves staged round-robin
// (A0,B0,A1,B1) one per phase; vmcnt(4) before each phase barrier keeps 2
// halves in flight (never drains to 0 in the main loop).
// Wave (wm,wn) owns rows {wm*64..+64} u {128+wm*64..+64} (A-halves 0/1) and
// cols {wn*32..+32} u {128+wn*32..+32} (B-halves 0/1) -> every wave's quadrant
// (mi,ni) touches exactly A-half mi / B-half ni, preserving the stagger.
__global__ __launch_bounds__(512, 2) void gemm_qkv8(
    const u16* xb, const u16* wqb, const u16* wkb, const u16* wvb,
    const float2* tab, u16* Qr, u16* Kr, u16* Vt)
{
  __shared__ __align__(16) u16 lds[2][2][2][128 * 64];

  const int bid = blockIdx.x;
  const int xcd = bid & 7, v = bid >> 3;      // v 0..23
  const int mt = xcd * 2 + (v >= 12 ? 1 : 0);
  const int nt = (v >= 12) ? v - 12 : v;
  const int m0 = mt * 256;
  const int z = nt >> 2;                      // 0=Q 1=K 2=V
  const int n0z = (nt & 3) * 256;             // col base within z's 1024
  const u16* Wz = (z == 0) ? wqb : ((z == 1) ? wkb : wvb);

  const int tid = threadIdx.x;
  const int w8 = tid >> 6, lane = tid & 63;
  const int wm = w8 >> 2, wn = w8 & 3;
  const int l15 = lane & 15, g = lane >> 4;
  const int swb = ((lane & 7) * 16) ^ (((lane >> 3) & 7) << 4);  // pre-swizzled src byte

  f32x4 acc[8][4] = {};
  bf16x8 aF[2][4][2];   // cached A-frags, both halves
  bf16x8 bC[2][2];      // current B-half frags (reloaded at p2)

  auto stageA = [&](int buf, int h, int kt) {
#pragma unroll
    for (int i = 0; i < 2; ++i) {
      const int rb = i * 64 + w8 * 8;
      const int row = rb + (lane >> 3);
      gl_lds16((const char*)(xb + (size_t)(m0 + h * 128 + row) * DM + kt * 64) + swb,
               (char*)&lds[buf][0][h][0] + rb * 128);
    }
  };
  auto stageB = [&](int buf, int h, int kt) {
#pragma unroll
    for (int i = 0; i < 2; ++i) {
      const int rb = i * 64 + w8 * 8;
      const int row = rb + (lane >> 3);
      gl_lds16((const char*)(Wz + (size_t)(n0z + h * 128 + row) * DM + kt * 64) + swb,
               (char*)&lds[buf][1][h][0] + rb * 128);
    }
  };
  auto loadA = [&](int cur, int mi) {
#pragma unroll
    for (int f = 0; f < 4; ++f) {
      const int row = wm * 64 + f * 16 + l15;
#pragma unroll
      for (int kk = 0; kk < 2; ++kk)
        aF[mi][f][kk] = *(const bf16x8*)((const char*)&lds[cur][0][mi][0] + row * 128 +
                                         ((kk * 64 + g * 16) ^ ((row & 7) << 4)));
    }
  };
  auto loadB = [&](int cur, int ni) {
#pragma unroll
    for (int f = 0; f < 2; ++f) {
      const int row = wn * 32 + f * 16 + l15;
#pragma unroll
      for (int kk = 0; kk < 2; ++kk)
        bC[f][kk] = *(const bf16x8*)((const char*)&lds[cur][1][ni][0] + row * 128 +
                                     ((kk * 64 + g * 16) ^ ((row & 7) << 4)));
    }
  };
  auto quad = [&](int mi, int ni) {
    __builtin_amdgcn_s_setprio(1);
#pragma unroll
    for (int f = 0; f < 4; ++f)
#pragma unroll
      for (int f2 = 0; f2 < 2; ++f2)
#pragma unroll
        for (int kk = 0; kk < 2; ++kk)
          acc[mi * 4 + f][ni * 2 + f2] =
              MFMA16(aF[mi][f][kk], bC[f2][kk], acc[mi * 4 + f][ni * 2 + f2]);
    __builtin_amdgcn_s_setprio(0);
  };

  // prologue: tile 0's four halves (slots A0,B0,A1,B1)
  stageA(0, 0, 0); stageB(0, 0, 0); stageA(0, 1, 0); stageB(0, 1, 0);
  VMW(4);          // slots A0,B0 done after barrier
  BAR();

  for (int kt = 0; kt < 16; ++kt) {
    const int cur = kt & 1, nx = cur ^ 1;
    if (kt < 15) {
      // p0: quadrant (0,0)
      loadA(cur, 0); loadB(cur, 0);
      stageA(nx, 0, kt + 1);
      VMW(4); BAR(); quad(0, 0); BAR();
      // p1: quadrant (1,0)
      loadA(cur, 1);
      stageB(nx, 0, kt + 1);
      VMW(4); BAR(); quad(1, 0); BAR();
      // p2: quadrant (0,1)
      loadB(cur, 1);
      stageA(nx, 1, kt + 1);
      VMW(4); BAR(); quad(0, 1); BAR();
      // p3: quadrant (1,1)
      stageB(nx, 1, kt + 1);
      VMW(4); BAR(); quad(1, 1); BAR();
    } else {
      VMW(0); BAR();                 // once per kernel: drain last tile
      loadA(cur, 0); loadB(cur, 0); quad(0, 0);
      loadA(cur, 1);                quad(1, 0);
      loadB(cur, 1);                quad(0, 1);
                                    quad(1, 1);
    }
  }

  // epilogue: RoPE (z<2) / V-transpose (z==2)
#pragma unroll
  for (int fm = 0; fm < 8; ++fm) {
    const int mrow = m0 + (fm >> 2) * 128 + wm * 64 + (fm & 3) * 16 + g * 4;
#pragma unroll
    for (int fn = 0; fn < 4; ++fn) {
      const int col = n0z + (fn >> 1) * 128 + wn * 32 + (fn & 1) * 16 + l15;
      const int h = col >> 6, d = col & 63;
#pragma unroll
      for (int r = 0; r < 4; ++r) {
        const int m = mrow + r;
        const int b = m >> 11, s = m & 2047;
        float vv = acc[fm][fn][r];
        if (z < 2) {
          float p = __shfl_xor(vv, 1);
          float2 cs = tab[s * 32 + (d >> 1)];
          float o = vv * cs.x + ((d & 1) ? p : -p) * cs.y;
          if (z == 0) o *= 0.125f;            // fold 1/sqrt(DK) into Q
          u16* dst = (z == 0) ? Qr : Kr;
          dst[((size_t)(b * NH + h) * S_LEN + s) * DK + d] = f2bf(o);
        } else {
          Vt[((size_t)(b * NH + h) * DK + d) * S_LEN + s] = f2bf(vv);
        }
      }
    }
  }
}

// ---------------- 2-phase 128x128 core (for gemm_out) ----------------
__device__ __forceinline__ void gemm_core_128_db(
    const u16* A, const u16* W, int K, int m0, int n0,
    u16 (&ldsA)[2][128 * 64], u16 (&ldsB)[2][128 * 64], f32x4 (&acc)[4][4])
{
  const int tid = threadIdx.x;
  const int w = tid >> 6, lane = tid & 63;
  const int l15 = lane & 15, g = lane >> 4;
  const int wm = (w >> 1) * 64, wn = (w & 1) * 64;
  const int lrow = lane >> 3;
  const int scolb = ((lane & 7) * 16) ^ (lrow << 4);

  auto stage = [&](int buf, int kt) {
#pragma unroll
    for (int c = 0; c < 4; ++c) {
      const int rb = w * 32 + c * 8;
      const int row = rb + lrow;
      gl_lds16((const char*)(A + (size_t)(m0 + row) * K + kt) + scolb,
               (char*)&ldsA[buf][0] + rb * 128);
      gl_lds16((const char*)(W + (size_t)(n0 + row) * K + kt) + scolb,
               (char*)&ldsB[buf][0] + rb * 128);
    }
  };

  stage(0, 0);
  __syncthreads();
  int cur = 0;
  for (int kt = 0; kt < K; kt += 64) {
    if (kt + 64 < K) stage(cur ^ 1, kt + 64);
#pragma unroll
    for (int ks = 0; ks < 2; ++ks) {
      bf16x8 af[4], bfr[4];
#pragma unroll
      for (int i = 0; i < 4; ++i) {
        const int ar = wm + i * 16 + l15;
        af[i] = *(const bf16x8*)((const char*)&ldsA[cur][0] + ar * 128 +
                                 ((ks * 64 + g * 16) ^ ((ar & 7) << 4)));
        const int br = wn + i * 16 + l15;
        bfr[i] = *(const bf16x8*)((const char*)&ldsB[cur][0] + br * 128 +
                                  ((ks * 64 + g * 16) ^ ((br & 7) << 4)));
      }
#pragma unroll
      for (int i = 0; i < 4; ++i)
#pragma unroll
        for (int j = 0; j < 4; ++j)
          acc[i][j] = MFMA16(af[i], bfr[j], acc[i][j]);
    }
    __syncthreads();
    cur ^= 1;
  }
}

__device__ __forceinline__ void xcd_map(int bid, int& m0, int& n0) {
  const int xcd = bid & 7, v = bid >> 3;
  m0 = (xcd * 4 + (v >> 3)) * 128;
  n0 = (v & 7) * 128;
}

__global__ __launch_bounds__(256) void gemm_out(const u16* ctx, const u16* wob, float* out) {
  __shared__ __align__(16) u16 ldsA[2][128 * 64];
  __shared__ __align__(16) u16 ldsB[2][128 * 64];
  int m0, n0;
  xcd_map(blockIdx.x, m0, n0);
  f32x4 acc[4][4] = {};
  gemm_core_128_db(ctx, wob, DM, m0, n0, ldsA, ldsB, acc);

  const int tid = threadIdx.x, w = tid >> 6, lane = tid & 63;
  const int l15 = lane & 15, g = lane >> 4;
  const int wm = (w >> 1) * 64, wn = (w & 1) * 64;
#pragma unroll
  for (int i = 0; i < 4; ++i)
#pragma unroll
    for (int j = 0; j < 4; ++j)
#pragma unroll
      for (int r = 0; r < 4; ++r)
        out[(size_t)(m0 + wm + i * 16 + g * 4 + r) * DM + n0 + wn + j * 16 + l15] = acc[i][j][r];
}

// ---------------- causal flash attention (balanced pairing, prefetched LDS K/V) ----------------
__global__ __launch_bounds__(256) void attn3(
    const u16* Qr, const u16* Kr, const u16* Vt, const int* amask, u16* ctx)
{
  __shared__ __align__(16) u16 ldsK[2][64 * 64];
  __shared__ __align__(16) u16 ldsV[2][64 * 64];
  __shared__ __align__(16) u16 plds[4][16 * 72];

  const int ip = blockIdx.x;          // 0..15
  const int bh = blockIdx.y;
  const int b = bh >> 4, h = bh & 15;
  const int qcA = ip, qcB = 31 - ip;
  const int tid = threadIdx.x, w = tid >> 6, lane = tid & 63;
  const int l15 = lane & 15, g = lane >> 4;
  const int r8 = lane >> 3;
  const int sw = ((lane & 7) * 16) ^ (r8 << 4);

  const u16* Kb0 = Kr + (size_t)bh * S_LEN * DK;
  const u16* Vb0 = Vt + (size_t)bh * DK * S_LEN;
  const u16* Qb  = Qr + (size_t)bh * S_LEN * DK;

  const int qA0 = qcA * 64 + w * 16;
  const int qB0 = qcB * 64 + w * 16;
  bf16x8 qaA[2], qaB[2];
  qaA[0] = *(const bf16x8*)(Qb + (size_t)(qA0 + l15) * DK + g * 8);
  qaA[1] = *(const bf16x8*)(Qb + (size_t)(qA0 + l15) * DK + 32 + g * 8);
  qaB[0] = *(const bf16x8*)(Qb + (size_t)(qB0 + l15) * DK + g * 8);
  qaB[1] = *(const bf16x8*)(Qb + (size_t)(qB0 + l15) * DK + 32 + g * 8);

  union { u16 u[8]; bf16x8 v; } one_u;
#pragma unroll
  for (int i = 0; i < 8; ++i) one_u.u[i] = 0x3F80;
  const bf16x8 ones = one_u.v;

  float mA[4], mB[4];
  f32x4 lA = {0.f, 0.f, 0.f, 0.f}, lB = {0.f, 0.f, 0.f, 0.f};
  f32x4 oA[4], oB[4];
#pragma unroll
  for (int r = 0; r < 4; ++r) { mA[r] = mB[r] = -3e38f; }
#pragma unroll
  for (int dt = 0; dt < 4; ++dt) {
    oA[dt] = (f32x4){0.f, 0.f, 0.f, 0.f};
    oB[dt] = (f32x4){0.f, 0.f, 0.f, 0.f};
  }

  auto stage = [&](int buf, int t) {
    const size_t kv0 = (size_t)t * 64;
#pragma unroll
    for (int c = 0; c < 2; ++c) {
      const int rb = c * 32 + w * 8;
      const int row = rb + r8;
      gl_lds16((const char*)(Kb0 + (kv0 + row) * DK) + sw,
               (char*)&ldsK[buf][0] + rb * 128);
      gl_lds16((const char*)(Vb0 + (size_t)row * S_LEN + kv0) + sw,
               (char*)&ldsV[buf][0] + rb * 128);
    }
  };

  stage(0, 0);
  const int ntB = qcB + 1;
  int cur = 0;
  __syncthreads();

  for (int t = 0; t < ntB; ++t) {
    if (t + 1 < ntB) stage(cur ^ 1, t + 1);
    const int kv0 = t * 64;
    int pm[4];
#pragma unroll
    for (int nt = 0; nt < 4; ++nt) pm[nt] = amask[b * S_LEN + kv0 + nt * 16 + l15];

    bf16x8 kb[4][2];
#pragma unroll
    for (int nt = 0; nt < 4; ++nt) {
      const int row = nt * 16 + l15;
#pragma unroll
      for (int ks = 0; ks < 2; ++ks)
        kb[nt][ks] = *(const bf16x8*)((const char*)&ldsK[cur][0] + row * 128 +
                                      ((ks * 64 + g * 16) ^ ((row & 7) << 4)));
    }
    const bool actA = (t <= qcA);
    f32x4 sA[4], sB[4];
#pragma unroll
    for (int nt = 0; nt < 4; ++nt) {
      sA[nt] = (f32x4){0.f, 0.f, 0.f, 0.f};
      sB[nt] = (f32x4){0.f, 0.f, 0.f, 0.f};
    }
    __builtin_amdgcn_s_setprio(1);
    if (actA) {
#pragma unroll
      for (int nt = 0; nt < 4; ++nt) {
        sA[nt] = MFMA16(qaA[0], kb[nt][0], sA[nt]);
        sA[nt] = MFMA16(qaA[1], kb[nt][1], sA[nt]);
      }
    }
#pragma unroll
    for (int nt = 0; nt < 4; ++nt) {
      sB[nt] = MFMA16(qaB[0], kb[nt][0], sB[nt]);
      sB[nt] = MFMA16(qaB[1], kb[nt][1], sB[nt]);
    }
    __builtin_amdgcn_s_setprio(0);

    bf16x8 vb[4][2];
#pragma unroll
    for (int dt = 0; dt < 4; ++dt) {
      const int row = dt * 16 + l15;
#pragma unroll
      for (int ks = 0; ks < 2; ++ks)
        vb[dt][ks] = *(const bf16x8*)((const char*)&ldsV[cur][0] + row * 128 +
                                      ((ks * 64 + g * 16) ^ ((row & 7) << 4)));
    }

    auto softmax_pv = [&](f32x4 (&s)[4], float (&m)[4], f32x4& lacc, f32x4 (&o)[4],
                          int q0, bool diag) {
      u16* pw = &plds[w][0];
#pragma unroll
      for (int nt = 0; nt < 4; ++nt) {
        const int kvc = kv0 + nt * 16 + l15;
#pragma unroll
        for (int r = 0; r < 4; ++r) {
          const bool ok = pm[nt] && (!diag || kvc <= q0 + g * 4 + r);
          s[nt][r] = ok ? s[nt][r] : -1e9f;
        }
      }
      float tmax[4];
      bool need = false;
#pragma unroll
      for (int r = 0; r < 4; ++r) {
        float t0 = fmaxf(fmaxf(s[0][r], s[1][r]), fmaxf(s[2][r], s[3][r]));
        t0 = fmaxf(t0, __shfl_xor(t0, 1));
        t0 = fmaxf(t0, __shfl_xor(t0, 2));
        t0 = fmaxf(t0, __shfl_xor(t0, 4));
        t0 = fmaxf(t0, __shfl_xor(t0, 8));
        tmax[r] = t0;
        need = need || (t0 > m[r] + 8.f);
      }
      if (__any((int)need)) {
#pragma unroll
        for (int r = 0; r < 4; ++r) {
          const float mnew = fmaxf(m[r], tmax[r]);
          const float alpha = __expf(m[r] - mnew);
          m[r] = mnew;
          lacc[r] *= alpha;
#pragma unroll
          for (int dt = 0; dt < 4; ++dt) o[dt][r] *= alpha;
        }
      }
#pragma unroll
      for (int r = 0; r < 4; ++r) {
#pragma unroll
        for (int nt = 0; nt < 4; ++nt)
          pw[(g * 4 + r) * 72 + nt * 16 + l15] = f2bf(__expf(s[nt][r] - m[r]));
      }
      bf16x8 pa0 = *(const bf16x8*)(pw + l15 * 72 + g * 8);
      bf16x8 pa1 = *(const bf16x8*)(pw + l15 * 72 + 32 + g * 8);
      __builtin_amdgcn_s_setprio(1);
      lacc = MFMA16(pa0, ones, lacc);
      lacc = MFMA16(pa1, ones, lacc);
#pragma unroll
      for (int dt = 0; dt < 4; ++dt) {
        o[dt] = MFMA16(pa0, vb[dt][0], o[dt]);
        o[dt] = MFMA16(pa1, vb[dt][1], o[dt]);
      }
      __builtin_amdgcn_s_setprio(0);
    };
    if (actA) softmax_pv(sA, mA, lA, oA, qA0, t == qcA);
    softmax_pv(sB, mB, lB, oB, qB0, t == qcB);

    __syncthreads();
    cur ^= 1;
  }

  auto wr = [&](f32x4& lacc, f32x4 (&o)[4], int q0) {
#pragma unroll
    for (int dt = 0; dt < 4; ++dt)
#pragma unroll
      for (int r = 0; r < 4; ++r) {
        const int q = q0 + g * 4 + r;
        ctx[((size_t)(b * S_LEN + q)) * DM + h * DK + dt * 16 + l15] =
            f2bf(o[dt][r] / lacc[r]);
      }
  };
  wr(lA, oA, qA0);
  wr(lB, oB, qB0);
}

extern "C" void kernel_launch(void* const* d_in, const int* in_sizes, int n_in,
                              void* d_out, int out_size, void* d_ws, size_t ws_size,
                              hipStream_t stream) {
  const float* x   = (const float*)d_in[0];
  const int* amask = (const int*)d_in[1];
  const float* wq  = (const float*)d_in[2];
  const float* wk  = (const float*)d_in[3];
  const float* wv  = (const float*)d_in[4];
  const float* wo  = (const float*)d_in[5];
  float* out = (float*)d_out;

  char* ws = (char*)d_ws;
  u16* xb    = (u16*)(ws);                      // 8 MB
  u16* wqb   = (u16*)(ws + ( 8u << 20));        // 2 MB
  u16* wkb   = (u16*)(ws + (10u << 20));
  u16* wvb   = (u16*)(ws + (12u << 20));
  u16* wob   = (u16*)(ws + (14u << 20));
  float2* tab = (float2*)(ws + (16u << 20));    // 512 KB
  u16* Qr    = (u16*)(ws + (17u << 20));        // 8 MB  [B,H,S,D]
  u16* Kr    = (u16*)(ws + (25u << 20));        // 8 MB  [B,H,S,D]
  u16* Vt    = (u16*)(ws + (33u << 20));        // 8 MB  [B,H,D,S]
  u16* ctx   = (u16*)(ws + (41u << 20));        // 8 MB  [B,S,H*D]

  hipLaunchKernelGGL(convert_all, dim3(8192), dim3(256), 0, stream,
                     x, wq, wk, wv, wo, xb, wqb, wkb, wvb, wob);
  hipLaunchKernelGGL(rope_tab_k, dim3(256), dim3(256), 0, stream, tab);
  hipLaunchKernelGGL(gemm_qkv8, dim3(192), dim3(512), 0, stream,
                     xb, wqb, wkb, wvb, tab, Qr, Kr, Vt);
  hipLaunchKernelGGL(attn3, dim3(16, 32), dim3(256), 0, stream, Qr, Kr, Vt, amask, ctx);
  hipLaunchKernelGGL(gemm_out, dim3(256), dim3(256), 0, stream, ctx, wob, out);
}

// Round 5
// 157.579 us; speedup vs baseline: 2.1741x; 1.0093x over previous
//
#include <hip/hip_runtime.h>
#include <hip/hip_bf16.h>
#include <cstdint>

typedef unsigned short u16;
typedef __bf16 bf16x8 __attribute__((ext_vector_type(8)));
typedef float f32x4 __attribute__((ext_vector_type(4)));

#define S_LEN 2048
#define NH 16
#define DK 64
#define DM 1024

__device__ __forceinline__ u16 f2bf(float f) {
  union { float f; uint32_t u; } c; c.f = f;
  uint32_t u = c.u;
  u += 0x7fffu + ((u >> 16) & 1u);   // RNE
  return (u16)(u >> 16);
}

__device__ __forceinline__ void gl_lds16(const void* gsrc, void* ldst) {
  __builtin_amdgcn_global_load_lds(
      (const __attribute__((address_space(1))) unsigned int*)gsrc,
      (__attribute__((address_space(3))) unsigned int*)ldst,
      16, 0, 0);
}

#define MFMA16(a, b, c) __builtin_amdgcn_mfma_f32_16x16x32_bf16((a), (b), (c), 0, 0, 0)
#define VMW(N) asm volatile("s_waitcnt vmcnt(" #N ")" ::: "memory")
#define BAR() __builtin_amdgcn_s_barrier()

// ---------------- fp32 -> bf16 conversion (x + 4 weights) ----------------
__global__ __launch_bounds__(256) void convert_all(
    const float* x, const float* wq, const float* wk, const float* wv, const float* wo,
    u16* xb, u16* wqb, u16* wkb, u16* wvb, u16* wob)
{
  size_t i = ((size_t)blockIdx.x * 256 + threadIdx.x) * 4;
  const float* src; u16* dst; size_t off;
  if (i < 4194304u)      { src = x;  dst = xb;  off = i; }
  else if (i < 5242880u) { src = wq; dst = wqb; off = i - 4194304u; }
  else if (i < 6291456u) { src = wk; dst = wkb; off = i - 5242880u; }
  else if (i < 7340032u) { src = wv; dst = wvb; off = i - 6291456u; }
  else                   { src = wo; dst = wob; off = i - 7340032u; }
  float4 v = *(const float4*)(src + off);
  ushort4 o;
  o.x = f2bf(v.x); o.y = f2bf(v.y); o.z = f2bf(v.z); o.w = f2bf(v.w);
  *(ushort4*)(dst + off) = o;
}

// ---------------- RoPE cos/sin table ----------------
__global__ __launch_bounds__(256) void rope_tab_k(float2* tab) {
  int i = blockIdx.x * 256 + threadIdx.x;   // 65536 entries
  int pos = i >> 5, f = i & 31;
  float inv = powf(10000.0f, -(float)f / 32.0f);
  float ang = (float)pos * inv;
  tab[i] = make_float2(cosf(ang), sinf(ang));
}

// ---------------- per-(b, kv-tile-of-64) all-valid flags ----------------
__global__ __launch_bounds__(64) void mask_flags(const int* amask, int* mflag) {
  const int f = blockIdx.x;               // 0..63: b = f>>5, tile = f&31
  const int b = f >> 5, t = f & 31;
  int v = amask[b * S_LEN + t * 64 + threadIdx.x];
  int all = (int)__all(v != 0);
  if (threadIdx.x == 0) mflag[f] = all;
}

// ================= fused QKV: 256x256 tile, 8 waves, 4-phase counted-vmcnt =================
__global__ __launch_bounds__(512, 2) void gemm_qkv8(
    const u16* xb, const u16* wqb, const u16* wkb, const u16* wvb,
    const float2* tab, u16* Qr, u16* Kr, u16* Vt)
{
  __shared__ __align__(16) u16 lds[2][2][2][128 * 64];

  const int bid = blockIdx.x;
  const int xcd = bid & 7, v = bid >> 3;      // v 0..23
  const int mt = xcd * 2 + (v >= 12 ? 1 : 0);
  const int nt = (v >= 12) ? v - 12 : v;
  const int m0 = mt * 256;
  const int z = nt >> 2;                      // 0=Q 1=K 2=V
  const int n0z = (nt & 3) * 256;
  const u16* Wz = (z == 0) ? wqb : ((z == 1) ? wkb : wvb);

  const int tid = threadIdx.x;
  const int w8 = tid >> 6, lane = tid & 63;
  const int wm = w8 >> 2, wn = w8 & 3;
  const int l15 = lane & 15, g = lane >> 4;
  const int swb = ((lane & 7) * 16) ^ (((lane >> 3) & 7) << 4);

  f32x4 acc[8][4] = {};
  bf16x8 aF[2][4][2];
  bf16x8 bC[2][2];

  auto stageA = [&](int buf, int h, int kt) {
#pragma unroll
    for (int i = 0; i < 2; ++i) {
      const int rb = i * 64 + w8 * 8;
      const int row = rb + (lane >> 3);
      gl_lds16((const char*)(xb + (size_t)(m0 + h * 128 + row) * DM + kt * 64) + swb,
               (char*)&lds[buf][0][h][0] + rb * 128);
    }
  };
  auto stageB = [&](int buf, int h, int kt) {
#pragma unroll
    for (int i = 0; i < 2; ++i) {
      const int rb = i * 64 + w8 * 8;
      const int row = rb + (lane >> 3);
      gl_lds16((const char*)(Wz + (size_t)(n0z + h * 128 + row) * DM + kt * 64) + swb,
               (char*)&lds[buf][1][h][0] + rb * 128);
    }
  };
  auto loadA = [&](int cur, int mi) {
#pragma unroll
    for (int f = 0; f < 4; ++f) {
      const int row = wm * 64 + f * 16 + l15;
#pragma unroll
      for (int kk = 0; kk < 2; ++kk)
        aF[mi][f][kk] = *(const bf16x8*)((const char*)&lds[cur][0][mi][0] + row * 128 +
                                         ((kk * 64 + g * 16) ^ ((row & 7) << 4)));
    }
  };
  auto loadB = [&](int cur, int ni) {
#pragma unroll
    for (int f = 0; f < 2; ++f) {
      const int row = wn * 32 + f * 16 + l15;
#pragma unroll
      for (int kk = 0; kk < 2; ++kk)
        bC[f][kk] = *(const bf16x8*)((const char*)&lds[cur][1][ni][0] + row * 128 +
                                     ((kk * 64 + g * 16) ^ ((row & 7) << 4)));
    }
  };
  auto quad = [&](int mi, int ni) {
    __builtin_amdgcn_s_setprio(1);
#pragma unroll
    for (int f = 0; f < 4; ++f)
#pragma unroll
      for (int f2 = 0; f2 < 2; ++f2)
#pragma unroll
        for (int kk = 0; kk < 2; ++kk)
          acc[mi * 4 + f][ni * 2 + f2] =
              MFMA16(aF[mi][f][kk], bC[f2][kk], acc[mi * 4 + f][ni * 2 + f2]);
    __builtin_amdgcn_s_setprio(0);
  };

  stageA(0, 0, 0); stageB(0, 0, 0); stageA(0, 1, 0); stageB(0, 1, 0);
  VMW(4);
  BAR();

  for (int kt = 0; kt < 16; ++kt) {
    const int cur = kt & 1, nx = cur ^ 1;
    if (kt < 15) {
      loadA(cur, 0); loadB(cur, 0);
      stageA(nx, 0, kt + 1);
      VMW(4); BAR(); quad(0, 0); BAR();
      loadA(cur, 1);
      stageB(nx, 0, kt + 1);
      VMW(4); BAR(); quad(1, 0); BAR();
      loadB(cur, 1);
      stageA(nx, 1, kt + 1);
      VMW(4); BAR(); quad(0, 1); BAR();
      stageB(nx, 1, kt + 1);
      VMW(4); BAR(); quad(1, 1); BAR();
    } else {
      VMW(0); BAR();
      loadA(cur, 0); loadB(cur, 0); quad(0, 0);
      loadA(cur, 1);                quad(1, 0);
      loadB(cur, 1);                quad(0, 1);
                                    quad(1, 1);
    }
  }

#pragma unroll
  for (int fm = 0; fm < 8; ++fm) {
    const int mrow = m0 + (fm >> 2) * 128 + wm * 64 + (fm & 3) * 16 + g * 4;
#pragma unroll
    for (int fn = 0; fn < 4; ++fn) {
      const int col = n0z + (fn >> 1) * 128 + wn * 32 + (fn & 1) * 16 + l15;
      const int h = col >> 6, d = col & 63;
#pragma unroll
      for (int r = 0; r < 4; ++r) {
        const int m = mrow + r;
        const int b = m >> 11, s = m & 2047;
        float vv = acc[fm][fn][r];
        if (z < 2) {
          float p = __shfl_xor(vv, 1);
          float2 cs = tab[s * 32 + (d >> 1)];
          float o = vv * cs.x + ((d & 1) ? p : -p) * cs.y;
          if (z == 0) o *= 0.125f;            // fold 1/sqrt(DK) into Q
          u16* dst = (z == 0) ? Qr : Kr;
          dst[((size_t)(b * NH + h) * S_LEN + s) * DK + d] = f2bf(o);
        } else {
          Vt[((size_t)(b * NH + h) * DK + d) * S_LEN + s] = f2bf(vv);
        }
      }
    }
  }
}

// ---------------- 2-phase 128x128 core (for gemm_out) ----------------
__device__ __forceinline__ void gemm_core_128_db(
    const u16* A, const u16* W, int K, int m0, int n0,
    u16 (&ldsA)[2][128 * 64], u16 (&ldsB)[2][128 * 64], f32x4 (&acc)[4][4])
{
  const int tid = threadIdx.x;
  const int w = tid >> 6, lane = tid & 63;
  const int l15 = lane & 15, g = lane >> 4;
  const int wm = (w >> 1) * 64, wn = (w & 1) * 64;
  const int lrow = lane >> 3;
  const int scolb = ((lane & 7) * 16) ^ (lrow << 4);

  auto stage = [&](int buf, int kt) {
#pragma unroll
    for (int c = 0; c < 4; ++c) {
      const int rb = w * 32 + c * 8;
      const int row = rb + lrow;
      gl_lds16((const char*)(A + (size_t)(m0 + row) * K + kt) + scolb,
               (char*)&ldsA[buf][0] + rb * 128);
      gl_lds16((const char*)(W + (size_t)(n0 + row) * K + kt) + scolb,
               (char*)&ldsB[buf][0] + rb * 128);
    }
  };

  stage(0, 0);
  __syncthreads();
  int cur = 0;
  for (int kt = 0; kt < K; kt += 64) {
    if (kt + 64 < K) stage(cur ^ 1, kt + 64);
#pragma unroll
    for (int ks = 0; ks < 2; ++ks) {
      bf16x8 af[4], bfr[4];
#pragma unroll
      for (int i = 0; i < 4; ++i) {
        const int ar = wm + i * 16 + l15;
        af[i] = *(const bf16x8*)((const char*)&ldsA[cur][0] + ar * 128 +
                                 ((ks * 64 + g * 16) ^ ((ar & 7) << 4)));
        const int br = wn + i * 16 + l15;
        bfr[i] = *(const bf16x8*)((const char*)&ldsB[cur][0] + br * 128 +
                                  ((ks * 64 + g * 16) ^ ((br & 7) << 4)));
      }
#pragma unroll
      for (int i = 0; i < 4; ++i)
#pragma unroll
        for (int j = 0; j < 4; ++j)
          acc[i][j] = MFMA16(af[i], bfr[j], acc[i][j]);
    }
    __syncthreads();
    cur ^= 1;
  }
}

__device__ __forceinline__ void xcd_map(int bid, int& m0, int& n0) {
  const int xcd = bid & 7, v = bid >> 3;
  m0 = (xcd * 4 + (v >> 3)) * 128;
  n0 = (v & 7) * 128;
}

__global__ __launch_bounds__(256) void gemm_out(const u16* ctx, const u16* wob, float* out) {
  __shared__ __align__(16) u16 ldsA[2][128 * 64];
  __shared__ __align__(16) u16 ldsB[2][128 * 64];
  int m0, n0;
  xcd_map(blockIdx.x, m0, n0);
  f32x4 acc[4][4] = {};
  gemm_core_128_db(ctx, wob, DM, m0, n0, ldsA, ldsB, acc);

  const int tid = threadIdx.x, w = tid >> 6, lane = tid & 63;
  const int l15 = lane & 15, g = lane >> 4;
  const int wm = (w >> 1) * 64, wn = (w & 1) * 64;
#pragma unroll
  for (int i = 0; i < 4; ++i)
#pragma unroll
    for (int j = 0; j < 4; ++j)
#pragma unroll
      for (int r = 0; r < 4; ++r)
        out[(size_t)(m0 + wm + i * 16 + g * 4 + r) * DM + n0 + wn + j * 16 + l15] = acc[i][j][r];
}

// ---------------- causal flash attention v4: 8 waves, 1 chunk per wave-pair ----------------
// Block ipair (0..15) owns 4 balanced 32-row q-chunks {i, 31-i, 32+i, 63-i}
// (130 half-tiles each -> equal work). Waves 2s,2s+1 own chunk s's rows.
// 512 blocks x 8 waves = 4096 waves = exactly 2 blocks/CU, no tail.
// K/V 64-kv tiles staged in LDS (swizzled, double-buffered, prefetched),
// shared by all 4 chunks. Pad mask skipped via per-tile mflag fast path.
__global__ __launch_bounds__(512, 4) void attn8(
    const u16* Qr, const u16* Kr, const u16* Vt, const int* amask, const int* mflag,
    u16* ctx)
{
  __shared__ __align__(16) u16 ldsK[2][64 * 64];
  __shared__ __align__(16) u16 ldsV[2][64 * 64];
  __shared__ __align__(16) __bf16 plds[8][16 * 72];   // per-wave P, 144B rows (16B-aligned)

  const int ipair = blockIdx.x;       // 0..15
  const int bh = blockIdx.y;
  const int b = bh >> 4, h = bh & 15;
  const int tid = threadIdx.x, w8 = tid >> 6, lane = tid & 63;
  const int l15 = lane & 15, g = lane >> 4;
  const int r8 = lane >> 3;
  const int sw = ((lane & 7) * 16) ^ (r8 << 4);

  const int sel = w8 >> 1;
  const int chunk = (sel == 0) ? ipair : (sel == 1) ? (31 - ipair)
                  : (sel == 2) ? (32 + ipair) : (63 - ipair);
  const int q0 = chunk * 32 + (w8 & 1) * 16;
  const int myNt = (chunk >> 1) + 1;   // tiles this chunk needs
  const int dTile = chunk >> 1;        // tile containing the causal diagonal
  const int ntB = ((63 - ipair) >> 1) + 1;   // block-wide tile count

  const u16* Kb0 = Kr + (size_t)bh * S_LEN * DK;
  const u16* Vb0 = Vt + (size_t)bh * DK * S_LEN;
  const u16* Qb  = Qr + (size_t)bh * S_LEN * DK;

  bf16x8 qa0 = *(const bf16x8*)(Qb + (size_t)(q0 + l15) * DK + g * 8);
  bf16x8 qa1 = *(const bf16x8*)(Qb + (size_t)(q0 + l15) * DK + 32 + g * 8);

  union { u16 u[8]; bf16x8 v; } one_u;
#pragma unroll
  for (int i = 0; i < 8; ++i) one_u.u[i] = 0x3F80;
  const bf16x8 ones = one_u.v;

  float m[4];
  f32x4 lacc = {0.f, 0.f, 0.f, 0.f};
  f32x4 o[4];
#pragma unroll
  for (int r = 0; r < 4; ++r) m[r] = -3e38f;
#pragma unroll
  for (int dt = 0; dt < 4; ++dt) o[dt] = (f32x4){0.f, 0.f, 0.f, 0.f};

  auto stage = [&](int buf, int t) {
    const size_t kv0 = (size_t)t * 64;
    const int row = w8 * 8 + r8;
    gl_lds16((const char*)(Kb0 + (kv0 + row) * DK) + sw,
             (char*)&ldsK[buf][0] + (w8 * 8) * 128);
    gl_lds16((const char*)(Vb0 + (size_t)row * S_LEN + kv0) + sw,
             (char*)&ldsV[buf][0] + (w8 * 8) * 128);
  };

  stage(0, 0);
  __syncthreads();
  int cur = 0;

  for (int t = 0; t < ntB; ++t) {
    if (t + 1 < ntB) stage(cur ^ 1, t + 1);
    if (t < myNt) {
      const int kv0 = t * 64;
      const bool allok = mflag[(b << 5) + t] != 0;

      bf16x8 kb[4][2];
#pragma unroll
      for (int nt = 0; nt < 4; ++nt) {
        const int row = nt * 16 + l15;
#pragma unroll
        for (int ks = 0; ks < 2; ++ks)
          kb[nt][ks] = *(const bf16x8*)((const char*)&ldsK[cur][0] + row * 128 +
                                        ((ks * 64 + g * 16) ^ ((row & 7) << 4)));
      }
      f32x4 s[4];
#pragma unroll
      for (int nt = 0; nt < 4; ++nt) s[nt] = (f32x4){0.f, 0.f, 0.f, 0.f};
      __builtin_amdgcn_s_setprio(1);
#pragma unroll
      for (int nt = 0; nt < 4; ++nt) {
        s[nt] = MFMA16(qa0, kb[nt][0], s[nt]);
        s[nt] = MFMA16(qa1, kb[nt][1], s[nt]);
      }
      __builtin_amdgcn_s_setprio(0);

      if (!allok) {                          // rare: pad-mask path
#pragma unroll
        for (int nt = 0; nt < 4; ++nt) {
          const int pmv = amask[b * S_LEN + kv0 + nt * 16 + l15];
#pragma unroll
          for (int r = 0; r < 4; ++r)
            if (!pmv) s[nt][r] = -1e9f;
        }
      }
      if (t == dTile) {                      // causal mask, diagonal tile only
#pragma unroll
        for (int nt = 0; nt < 4; ++nt) {
          const int kvc = kv0 + nt * 16 + l15;
#pragma unroll
          for (int r = 0; r < 4; ++r)
            s[nt][r] = (kvc <= q0 + g * 4 + r) ? s[nt][r] : -1e9f;
        }
      }

      float tmax[4];
      bool need = false;
#pragma unroll
      for (int r = 0; r < 4; ++r) {
        float t0 = fmaxf(fmaxf(s[0][r], s[1][r]), fmaxf(s[2][r], s[3][r]));
        t0 = fmaxf(t0, __shfl_xor(t0, 1));
        t0 = fmaxf(t0, __shfl_xor(t0, 2));
        t0 = fmaxf(t0, __shfl_xor(t0, 4));
        t0 = fmaxf(t0, __shfl_xor(t0, 8));
        tmax[r] = t0;
        need = need || (t0 > m[r] + 8.f);
      }
      if (__any((int)need)) {                // T13: rescale only on growth
#pragma unroll
        for (int r = 0; r < 4; ++r) {
          const float mnew = fmaxf(m[r], tmax[r]);
          const float alpha = __expf(m[r] - mnew);
          m[r] = mnew;
          lacc[r] *= alpha;
#pragma unroll
          for (int dt = 0; dt < 4; ++dt) o[dt][r] *= alpha;
        }
      }
      __bf16* pw = &plds[w8][0];
#pragma unroll
      for (int r = 0; r < 4; ++r) {
#pragma unroll
        for (int nt = 0; nt < 4; ++nt)
          pw[(g * 4 + r) * 72 + nt * 16 + l15] = (__bf16)__expf(s[nt][r] - m[r]);
      }
      bf16x8 pa0 = *(const bf16x8*)(pw + l15 * 72 + g * 8);
      bf16x8 pa1 = *(const bf16x8*)(pw + l15 * 72 + 32 + g * 8);
      bf16x8 vb[4][2];
#pragma unroll
      for (int dt = 0; dt < 4; ++dt) {
        const int row = dt * 16 + l15;
#pragma unroll
        for (int ks = 0; ks < 2; ++ks)
          vb[dt][ks] = *(const bf16x8*)((const char*)&ldsV[cur][0] + row * 128 +
                                        ((ks * 64 + g * 16) ^ ((row & 7) << 4)));
      }
      __builtin_amdgcn_s_setprio(1);
      lacc = MFMA16(pa0, ones, lacc);
      lacc = MFMA16(pa1, ones, lacc);
#pragma unroll
      for (int dt = 0; dt < 4; ++dt) {
        o[dt] = MFMA16(pa0, vb[dt][0], o[dt]);
        o[dt] = MFMA16(pa1, vb[dt][1], o[dt]);
      }
      __builtin_amdgcn_s_setprio(0);
    }
    __syncthreads();
    cur ^= 1;
  }

#pragma unroll
  for (int dt = 0; dt < 4; ++dt)
#pragma unroll
    for (int r = 0; r < 4; ++r) {
      const int q = q0 + g * 4 + r;
      ctx[((size_t)(b * S_LEN + q)) * DM + h * DK + dt * 16 + l15] =
          f2bf(o[dt][r] / lacc[r]);
    }
}

extern "C" void kernel_launch(void* const* d_in, const int* in_sizes, int n_in,
                              void* d_out, int out_size, void* d_ws, size_t ws_size,
                              hipStream_t stream) {
  const float* x   = (const float*)d_in[0];
  const int* amask = (const int*)d_in[1];
  const float* wq  = (const float*)d_in[2];
  const float* wk  = (const float*)d_in[3];
  const float* wv  = (const float*)d_in[4];
  const float* wo  = (const float*)d_in[5];
  float* out = (float*)d_out;

  char* ws = (char*)d_ws;
  u16* xb    = (u16*)(ws);                      // 8 MB
  u16* wqb   = (u16*)(ws + ( 8u << 20));        // 2 MB
  u16* wkb   = (u16*)(ws + (10u << 20));
  u16* wvb   = (u16*)(ws + (12u << 20));
  u16* wob   = (u16*)(ws + (14u << 20));
  float2* tab = (float2*)(ws + (16u << 20));    // 512 KB
  int* mflag = (int*)(ws + (16u << 20) + (768u << 10));   // 256 B
  u16* Qr    = (u16*)(ws + (17u << 20));        // 8 MB  [B,H,S,D]
  u16* Kr    = (u16*)(ws + (25u << 20));        // 8 MB  [B,H,S,D]
  u16* Vt    = (u16*)(ws + (33u << 20));        // 8 MB  [B,H,D,S]
  u16* ctx   = (u16*)(ws + (41u << 20));        // 8 MB  [B,S,H*D]

  hipLaunchKernelGGL(convert_all, dim3(8192), dim3(256), 0, stream,
                     x, wq, wk, wv, wo, xb, wqb, wkb, wvb, wob);
  hipLaunchKernelGGL(rope_tab_k, dim3(256), dim3(256), 0, stream, tab);
  hipLaunchKernelGGL(mask_flags, dim3(64), dim3(64), 0, stream, amask, mflag);
  hipLaunchKernelGGL(gemm_qkv8, dim3(192), dim3(512), 0, stream,
                     xb, wqb, wkb, wvb, tab, Qr, Kr, Vt);
  hipLaunchKernelGGL(attn8, dim3(16, 32), dim3(512), 0, stream,
                     Qr, Kr, Vt, amask, mflag, ctx);
  hipLaunchKernelGGL(gemm_out, dim3(256), dim3(256), 0, stream, ctx, wob, out);
}

// Round 6
// 149.906 us; speedup vs baseline: 2.2854x; 1.0512x over previous
//
#include <hip/hip_runtime.h>
#include <hip/hip_bf16.h>
#include <cstdint>

typedef unsigned short u16;
typedef __bf16 bf16x8 __attribute__((ext_vector_type(8)));
typedef float f32x4 __attribute__((ext_vector_type(4)));

#define S_LEN 2048
#define NH 16
#define DK 64
#define DM 1024

__device__ __forceinline__ u16 f2bf(float f) {
  union { float f; uint32_t u; } c; c.f = f;
  uint32_t u = c.u;
  u += 0x7fffu + ((u >> 16) & 1u);   // RNE
  return (u16)(u >> 16);
}

__device__ __forceinline__ void gl_lds16(const void* gsrc, void* ldst) {
  __builtin_amdgcn_global_load_lds(
      (const __attribute__((address_space(1))) unsigned int*)gsrc,
      (__attribute__((address_space(3))) unsigned int*)ldst,
      16, 0, 0);
}

#define MFMA16(a, b, c) __builtin_amdgcn_mfma_f32_16x16x32_bf16((a), (b), (c), 0, 0, 0)
#define VMW(N) asm volatile("s_waitcnt vmcnt(" #N ")" ::: "memory")
#define BARM() asm volatile("s_barrier" ::: "memory")   // barrier + compiler mem-fence

// ---------------- fp32 -> bf16 conversion (x + 4 weights) ----------------
__global__ __launch_bounds__(256) void convert_all(
    const float* x, const float* wq, const float* wk, const float* wv, const float* wo,
    u16* xb, u16* wqb, u16* wkb, u16* wvb, u16* wob)
{
  size_t i = ((size_t)blockIdx.x * 256 + threadIdx.x) * 4;
  const float* src; u16* dst; size_t off;
  if (i < 4194304u)      { src = x;  dst = xb;  off = i; }
  else if (i < 5242880u) { src = wq; dst = wqb; off = i - 4194304u; }
  else if (i < 6291456u) { src = wk; dst = wkb; off = i - 5242880u; }
  else if (i < 7340032u) { src = wv; dst = wvb; off = i - 6291456u; }
  else                   { src = wo; dst = wob; off = i - 7340032u; }
  float4 v = *(const float4*)(src + off);
  ushort4 o;
  o.x = f2bf(v.x); o.y = f2bf(v.y); o.z = f2bf(v.z); o.w = f2bf(v.w);
  *(ushort4*)(dst + off) = o;
}

// ---------------- RoPE cos/sin table ----------------
__global__ __launch_bounds__(256) void rope_tab_k(float2* tab) {
  int i = blockIdx.x * 256 + threadIdx.x;   // 65536 entries
  int pos = i >> 5, f = i & 31;
  float inv = powf(10000.0f, -(float)f / 32.0f);
  float ang = (float)pos * inv;
  tab[i] = make_float2(cosf(ang), sinf(ang));
}

// ---------------- per-(b, kv-tile-of-64) all-valid flags ----------------
__global__ __launch_bounds__(64) void mask_flags(const int* amask, int* mflag) {
  const int f = blockIdx.x;               // 0..63: b = f>>5, tile = f&31
  const int b = f >> 5, t = f & 31;
  int v = amask[b * S_LEN + t * 64 + threadIdx.x];
  int all = (int)__all(v != 0);
  if (threadIdx.x == 0) mflag[f] = all;
}

// ================= fused QKV: 256x256 tile, 8 waves, 4-phase counted-vmcnt =================
// Phase = { stage next-half ; VMW(6) ; s_barrier ; ds_load this-half ; 16 MFMA }.
// vmcnt ledger (steady state, halves in issue order A0,B0,A1,B1 round-robin):
//   entering p0: {B0,A1,B1}=6 ; +stage A0' ->8 ; VMW(6) drains B0 (this phase's read)
//   p1 drains A1, p2 drains B1, p3 drains A0' -> each half drains exactly one
//   full K-tile (4 phases) after issue. Last tile: VMW 4/2/0 ladder.
// Tile-boundary WAR: a half's last ds_read and its re-stage are >=3 barriers apart.
__global__ __launch_bounds__(512, 2) void gemm_qkv8(
    const u16* xb, const u16* wqb, const u16* wkb, const u16* wvb,
    const float2* tab, u16* Qr, u16* Kr, u16* Vt)
{
  __shared__ __align__(16) u16 lds[2][2][2][128 * 64];

  const int bid = blockIdx.x;
  const int xcd = bid & 7, v = bid >> 3;      // v 0..23
  const int mt = xcd * 2 + (v >= 12 ? 1 : 0);
  const int nt = (v >= 12) ? v - 12 : v;
  const int m0 = mt * 256;
  const int z = nt >> 2;                      // 0=Q 1=K 2=V
  const int n0z = (nt & 3) * 256;
  const u16* Wz = (z == 0) ? wqb : ((z == 1) ? wkb : wvb);

  const int tid = threadIdx.x;
  const int w8 = tid >> 6, lane = tid & 63;
  const int wm = w8 >> 2, wn = w8 & 3;
  const int l15 = lane & 15, g = lane >> 4;
  const int swb = ((lane & 7) * 16) ^ (((lane >> 3) & 7) << 4);

  f32x4 acc[8][4] = {};
  bf16x8 aF[2][4][2];
  bf16x8 bC[2][2];

  auto stageA = [&](int buf, int h, int kt) {
#pragma unroll
    for (int i = 0; i < 2; ++i) {
      const int rb = i * 64 + w8 * 8;
      const int row = rb + (lane >> 3);
      gl_lds16((const char*)(xb + (size_t)(m0 + h * 128 + row) * DM + kt * 64) + swb,
               (char*)&lds[buf][0][h][0] + rb * 128);
    }
  };
  auto stageB = [&](int buf, int h, int kt) {
#pragma unroll
    for (int i = 0; i < 2; ++i) {
      const int rb = i * 64 + w8 * 8;
      const int row = rb + (lane >> 3);
      gl_lds16((const char*)(Wz + (size_t)(n0z + h * 128 + row) * DM + kt * 64) + swb,
               (char*)&lds[buf][1][h][0] + rb * 128);
    }
  };
  auto loadA = [&](int cur, int mi) {
#pragma unroll
    for (int f = 0; f < 4; ++f) {
      const int row = wm * 64 + f * 16 + l15;
#pragma unroll
      for (int kk = 0; kk < 2; ++kk)
        aF[mi][f][kk] = *(const bf16x8*)((const char*)&lds[cur][0][mi][0] + row * 128 +
                                         ((kk * 64 + g * 16) ^ ((row & 7) << 4)));
    }
  };
  auto loadB = [&](int cur, int ni) {
#pragma unroll
    for (int f = 0; f < 2; ++f) {
      const int row = wn * 32 + f * 16 + l15;
#pragma unroll
      for (int kk = 0; kk < 2; ++kk)
        bC[f][kk] = *(const bf16x8*)((const char*)&lds[cur][1][ni][0] + row * 128 +
                                     ((kk * 64 + g * 16) ^ ((row & 7) << 4)));
    }
  };
  auto quad = [&](int mi, int ni) {
    __builtin_amdgcn_s_setprio(1);
#pragma unroll
    for (int f = 0; f < 4; ++f)
#pragma unroll
      for (int f2 = 0; f2 < 2; ++f2)
#pragma unroll
        for (int kk = 0; kk < 2; ++kk)
          acc[mi * 4 + f][ni * 2 + f2] =
              MFMA16(aF[mi][f][kk], bC[f2][kk], acc[mi * 4 + f][ni * 2 + f2]);
    __builtin_amdgcn_s_setprio(0);
  };

  // prologue: tile 0's four halves (issue order A0,B0,A1,B1 = 8 outstanding)
  stageA(0, 0, 0); stageB(0, 0, 0); stageA(0, 1, 0); stageB(0, 1, 0);

  for (int kt = 0; kt < 16; ++kt) {
    const int cur = kt & 1, nx = cur ^ 1;
    const bool pf = (kt < 15);
    // p0: quadrant (0,0) — reads A0,B0
    if (pf) { stageA(nx, 0, kt + 1); VMW(6); } else { VMW(4); }
    BARM();
    loadA(cur, 0); loadB(cur, 0);
    quad(0, 0);
    // p1: quadrant (1,0) — reads A1 (B0 cached)
    if (pf) { stageB(nx, 0, kt + 1); VMW(6); } else { VMW(2); }
    BARM();
    loadA(cur, 1);
    quad(1, 0);
    // p2: quadrant (0,1) — reads B1 (A0 cached)
    if (pf) { stageA(nx, 1, kt + 1); VMW(6); } else { VMW(0); }
    BARM();
    loadB(cur, 1);
    quad(0, 1);
    // p3: quadrant (1,1) — regs only
    if (pf) { stageB(nx, 1, kt + 1); VMW(6); }
    BARM();
    quad(1, 1);
  }

  // epilogue: RoPE (z<2) / V-transpose (z==2)
#pragma unroll
  for (int fm = 0; fm < 8; ++fm) {
    const int mrow = m0 + (fm >> 2) * 128 + wm * 64 + (fm & 3) * 16 + g * 4;
#pragma unroll
    for (int fn = 0; fn < 4; ++fn) {
      const int col = n0z + (fn >> 1) * 128 + wn * 32 + (fn & 1) * 16 + l15;
      const int h = col >> 6, d = col & 63;
#pragma unroll
      for (int r = 0; r < 4; ++r) {
        const int m = mrow + r;
        const int b = m >> 11, s = m & 2047;
        float vv = acc[fm][fn][r];
        if (z < 2) {
          float p = __shfl_xor(vv, 1);
          float2 cs = tab[s * 32 + (d >> 1)];
          float o = vv * cs.x + ((d & 1) ? p : -p) * cs.y;
          if (z == 0) o *= 0.125f;            // fold 1/sqrt(DK) into Q
          u16* dst = (z == 0) ? Qr : Kr;
          dst[((size_t)(b * NH + h) * S_LEN + s) * DK + d] = f2bf(o);
        } else {
          Vt[((size_t)(b * NH + h) * DK + d) * S_LEN + s] = f2bf(vv);
        }
      }
    }
  }
}

// ---------------- output GEMM: counted-vmcnt double-buffered 128x128 ----------------
__device__ __forceinline__ void xcd_map(int bid, int& m0, int& n0) {
  const int xcd = bid & 7, v = bid >> 3;
  m0 = (xcd * 4 + (v >> 3)) * 128;
  n0 = (v & 7) * 128;
}

__global__ __launch_bounds__(256) void gemm_out(const u16* ctx, const u16* wob, float* out) {
  __shared__ __align__(16) u16 ldsA[2][128 * 64];
  __shared__ __align__(16) u16 ldsB[2][128 * 64];
  int m0, n0;
  xcd_map(blockIdx.x, m0, n0);

  const int tid = threadIdx.x;
  const int w = tid >> 6, lane = tid & 63;
  const int l15 = lane & 15, g = lane >> 4;
  const int wm = (w >> 1) * 64, wn = (w & 1) * 64;
  const int lrow = lane >> 3;
  const int scolb = ((lane & 7) * 16) ^ (lrow << 4);
  f32x4 acc[4][4] = {};

  auto stage = [&](int buf, int kt) {
#pragma unroll
    for (int c = 0; c < 4; ++c) {
      const int rb = w * 32 + c * 8;
      const int row = rb + lrow;
      gl_lds16((const char*)(ctx + (size_t)(m0 + row) * DM + kt) + scolb,
               (char*)&ldsA[buf][0] + rb * 128);
      gl_lds16((const char*)(wob + (size_t)(n0 + row) * DM + kt) + scolb,
               (char*)&ldsB[buf][0] + rb * 128);
    }
  };

  stage(0, 0);                     // 8 outstanding
  int cur = 0;
  for (int kt = 0; kt < DM; kt += 64) {
    if (kt + 64 < DM) { stage(cur ^ 1, kt + 64); VMW(8); } else { VMW(0); }
    BARM();
#pragma unroll
    for (int ks = 0; ks < 2; ++ks) {
      bf16x8 af[4], bfr[4];
#pragma unroll
      for (int i = 0; i < 4; ++i) {
        const int ar = wm + i * 16 + l15;
        af[i] = *(const bf16x8*)((const char*)&ldsA[cur][0] + ar * 128 +
                                 ((ks * 64 + g * 16) ^ ((ar & 7) << 4)));
        const int br = wn + i * 16 + l15;
        bfr[i] = *(const bf16x8*)((const char*)&ldsB[cur][0] + br * 128 +
                                  ((ks * 64 + g * 16) ^ ((br & 7) << 4)));
      }
      __builtin_amdgcn_s_setprio(1);
#pragma unroll
      for (int i = 0; i < 4; ++i)
#pragma unroll
        for (int j = 0; j < 4; ++j)
          acc[i][j] = MFMA16(af[i], bfr[j], acc[i][j]);
      __builtin_amdgcn_s_setprio(0);
    }
    BARM();
    cur ^= 1;
  }

#pragma unroll
  for (int i = 0; i < 4; ++i)
#pragma unroll
    for (int j = 0; j < 4; ++j)
#pragma unroll
      for (int r = 0; r < 4; ++r)
        out[(size_t)(m0 + wm + i * 16 + g * 4 + r) * DM + n0 + wn + j * 16 + l15] = acc[i][j][r];
}

// ---------------- causal flash attention v5 ----------------
// Block (bh=blockIdx.x, g=15-blockIdx.y) owns 4 CONSECUTIVE 32-row q-chunks
// {4g..4g+3}: wave-pair depth spread <=1 -> ~zero wave idle; ntB = 2g+2.
// Longest blocks launch first -> descending-sorted greedy = ~uniform 34 tiles/CU.
// Counted vmcnt: stage(t+1); VMW(2); bar; compute(t); bar.
__global__ __launch_bounds__(512, 4) void attn9(
    const u16* Qr, const u16* Kr, const u16* Vt, const int* amask, const int* mflag,
    u16* ctx)
{
  __shared__ __align__(16) u16 ldsK[2][64 * 64];
  __shared__ __align__(16) u16 ldsV[2][64 * 64];
  __shared__ __align__(16) __bf16 plds[8][16 * 72];

  const int bh = blockIdx.x;
  const int grp = 15 - blockIdx.y;     // longest first
  const int b = bh >> 4, h = bh & 15;
  const int tid = threadIdx.x, w8 = tid >> 6, lane = tid & 63;
  const int l15 = lane & 15, g = lane >> 4;
  const int r8 = lane >> 3;
  const int sw = ((lane & 7) * 16) ^ (r8 << 4);

  const int chunk = grp * 4 + (w8 >> 1);          // 32-row chunk, 0..63
  const int q0 = chunk * 32 + (w8 & 1) * 16;
  const int myNt = (chunk >> 1) + 1;
  const int dTile = chunk >> 1;
  const int ntB = grp * 2 + 2;

  const u16* Kb0 = Kr + (size_t)bh * S_LEN * DK;
  const u16* Vb0 = Vt + (size_t)bh * DK * S_LEN;
  const u16* Qb  = Qr + (size_t)bh * S_LEN * DK;

  bf16x8 qa0 = *(const bf16x8*)(Qb + (size_t)(q0 + l15) * DK + g * 8);
  bf16x8 qa1 = *(const bf16x8*)(Qb + (size_t)(q0 + l15) * DK + 32 + g * 8);

  union { u16 u[8]; bf16x8 v; } one_u;
#pragma unroll
  for (int i = 0; i < 8; ++i) one_u.u[i] = 0x3F80;
  const bf16x8 ones = one_u.v;

  float m[4];
  f32x4 lacc = {0.f, 0.f, 0.f, 0.f};
  f32x4 o[4];
#pragma unroll
  for (int r = 0; r < 4; ++r) m[r] = -3e38f;
#pragma unroll
  for (int dt = 0; dt < 4; ++dt) o[dt] = (f32x4){0.f, 0.f, 0.f, 0.f};

  auto stage = [&](int buf, int t) {
    const size_t kv0 = (size_t)t * 64;
    const int row = w8 * 8 + r8;
    gl_lds16((const char*)(Kb0 + (kv0 + row) * DK) + sw,
             (char*)&ldsK[buf][0] + (w8 * 8) * 128);
    gl_lds16((const char*)(Vb0 + (size_t)row * S_LEN + kv0) + sw,
             (char*)&ldsV[buf][0] + (w8 * 8) * 128);
  };

  stage(0, 0);
  int cur = 0;

  for (int t = 0; t < ntB; ++t) {
    if (t + 1 < ntB) { stage(cur ^ 1, t + 1); VMW(2); } else { VMW(0); }
    BARM();
    if (t < myNt) {
      const int kv0 = t * 64;
      const bool allok = mflag[(b << 5) + t] != 0;

      bf16x8 kb[4][2];
#pragma unroll
      for (int nt = 0; nt < 4; ++nt) {
        const int row = nt * 16 + l15;
#pragma unroll
        for (int ks = 0; ks < 2; ++ks)
          kb[nt][ks] = *(const bf16x8*)((const char*)&ldsK[cur][0] + row * 128 +
                                        ((ks * 64 + g * 16) ^ ((row & 7) << 4)));
      }
      f32x4 s[4];
#pragma unroll
      for (int nt = 0; nt < 4; ++nt) s[nt] = (f32x4){0.f, 0.f, 0.f, 0.f};
      __builtin_amdgcn_s_setprio(1);
#pragma unroll
      for (int nt = 0; nt < 4; ++nt) {
        s[nt] = MFMA16(qa0, kb[nt][0], s[nt]);
        s[nt] = MFMA16(qa1, kb[nt][1], s[nt]);
      }
      __builtin_amdgcn_s_setprio(0);

      if (!allok) {
#pragma unroll
        for (int nt = 0; nt < 4; ++nt) {
          const int pmv = amask[b * S_LEN + kv0 + nt * 16 + l15];
#pragma unroll
          for (int r = 0; r < 4; ++r)
            if (!pmv) s[nt][r] = -1e9f;
        }
      }
      if (t == dTile) {
#pragma unroll
        for (int nt = 0; nt < 4; ++nt) {
          const int kvc = kv0 + nt * 16 + l15;
#pragma unroll
          for (int r = 0; r < 4; ++r)
            s[nt][r] = (kvc <= q0 + g * 4 + r) ? s[nt][r] : -1e9f;
        }
      }

      float tmax[4];
      bool need = false;
#pragma unroll
      for (int r = 0; r < 4; ++r) {
        float t0 = fmaxf(fmaxf(s[0][r], s[1][r]), fmaxf(s[2][r], s[3][r]));
        t0 = fmaxf(t0, __shfl_xor(t0, 1));
        t0 = fmaxf(t0, __shfl_xor(t0, 2));
        t0 = fmaxf(t0, __shfl_xor(t0, 4));
        t0 = fmaxf(t0, __shfl_xor(t0, 8));
        tmax[r] = t0;
        need = need || (t0 > m[r] + 8.f);
      }
      if (__any((int)need)) {                // T13: rescale only on growth
#pragma unroll
        for (int r = 0; r < 4; ++r) {
          const float mnew = fmaxf(m[r], tmax[r]);
          const float alpha = __expf(m[r] - mnew);
          m[r] = mnew;
          lacc[r] *= alpha;
#pragma unroll
          for (int dt = 0; dt < 4; ++dt) o[dt][r] *= alpha;
        }
      }
      __bf16* pw = &plds[w8][0];
#pragma unroll
      for (int r = 0; r < 4; ++r) {
#pragma unroll
        for (int nt = 0; nt < 4; ++nt)
          pw[(g * 4 + r) * 72 + nt * 16 + l15] = (__bf16)__expf(s[nt][r] - m[r]);
      }
      bf16x8 pa0 = *(const bf16x8*)(pw + l15 * 72 + g * 8);
      bf16x8 pa1 = *(const bf16x8*)(pw + l15 * 72 + 32 + g * 8);
      bf16x8 vb[4][2];
#pragma unroll
      for (int dt = 0; dt < 4; ++dt) {
        const int row = dt * 16 + l15;
#pragma unroll
        for (int ks = 0; ks < 2; ++ks)
          vb[dt][ks] = *(const bf16x8*)((const char*)&ldsV[cur][0] + row * 128 +
                                        ((ks * 64 + g * 16) ^ ((row & 7) << 4)));
      }
      __builtin_amdgcn_s_setprio(1);
      lacc = MFMA16(pa0, ones, lacc);
      lacc = MFMA16(pa1, ones, lacc);
#pragma unroll
      for (int dt = 0; dt < 4; ++dt) {
        o[dt] = MFMA16(pa0, vb[dt][0], o[dt]);
        o[dt] = MFMA16(pa1, vb[dt][1], o[dt]);
      }
      __builtin_amdgcn_s_setprio(0);
    }
    BARM();
    cur ^= 1;
  }

#pragma unroll
  for (int dt = 0; dt < 4; ++dt)
#pragma unroll
    for (int r = 0; r < 4; ++r) {
      const int q = q0 + g * 4 + r;
      ctx[((size_t)(b * S_LEN + q)) * DM + h * DK + dt * 16 + l15] =
          f2bf(o[dt][r] / lacc[r]);
    }
}

extern "C" void kernel_launch(void* const* d_in, const int* in_sizes, int n_in,
                              void* d_out, int out_size, void* d_ws, size_t ws_size,
                              hipStream_t stream) {
  const float* x   = (const float*)d_in[0];
  const int* amask = (const int*)d_in[1];
  const float* wq  = (const float*)d_in[2];
  const float* wk  = (const float*)d_in[3];
  const float* wv  = (const float*)d_in[4];
  const float* wo  = (const float*)d_in[5];
  float* out = (float*)d_out;

  char* ws = (char*)d_ws;
  u16* xb    = (u16*)(ws);                      // 8 MB
  u16* wqb   = (u16*)(ws + ( 8u << 20));        // 2 MB
  u16* wkb   = (u16*)(ws + (10u << 20));
  u16* wvb   = (u16*)(ws + (12u << 20));
  u16* wob   = (u16*)(ws + (14u << 20));
  float2* tab = (float2*)(ws + (16u << 20));    // 512 KB
  int* mflag = (int*)(ws + (16u << 20) + (768u << 10));   // 256 B
  u16* Qr    = (u16*)(ws + (17u << 20));        // 8 MB  [B,H,S,D]
  u16* Kr    = (u16*)(ws + (25u << 20));        // 8 MB  [B,H,S,D]
  u16* Vt    = (u16*)(ws + (33u << 20));        // 8 MB  [B,H,D,S]
  u16* ctx   = (u16*)(ws + (41u << 20));        // 8 MB  [B,S,H*D]

  hipLaunchKernelGGL(convert_all, dim3(8192), dim3(256), 0, stream,
                     x, wq, wk, wv, wo, xb, wqb, wkb, wvb, wob);
  hipLaunchKernelGGL(rope_tab_k, dim3(256), dim3(256), 0, stream, tab);
  hipLaunchKernelGGL(mask_flags, dim3(64), dim3(64), 0, stream, amask, mflag);
  hipLaunchKernelGGL(gemm_qkv8, dim3(192), dim3(512), 0, stream,
                     xb, wqb, wkb, wvb, tab, Qr, Kr, Vt);
  hipLaunchKernelGGL(attn9, dim3(32, 16), dim3(512), 0, stream,
                     Qr, Kr, Vt, amask, mflag, ctx);
  hipLaunchKernelGGL(gemm_out, dim3(256), dim3(256), 0, stream, ctx, wob, out);
}